// Round 21
// baseline (509.483 us; speedup 1.0000x reference)
//
#include <hip/hip_runtime.h>

#define HW 65536          // 256*256
#define NPOS 262144       // B(4) * HW

typedef unsigned int   u32;
typedef unsigned short u16;
typedef __attribute__((ext_vector_type(8))) short v8s;
typedef __attribute__((ext_vector_type(4))) float f32x4;
typedef __attribute__((ext_vector_type(2))) float f32x2;

__device__ __forceinline__ float bf2f(u16 h){
  union { u32 u; float f; } c; c.u = ((u32)h) << 16; return c.f;
}
__device__ __forceinline__ u16 f2bf(float f){
  union { u32 u; float f; } c; c.f = f;
  u32 r = c.u + 0x7fffu + ((c.u >> 16) & 1u);
  return (u16)(r >> 16);
}
__device__ __forceinline__ u32 pk2(float a, float b){
  return (u32)f2bf(a) | ((u32)f2bf(b) << 16);
}
__device__ __forceinline__ v8s as8(uint4 u){
  union { uint4 a; v8s b; } c; c.a = u; return c.b;
}
__device__ __forceinline__ f32x2 up2(u32 u){
  union { u32 u; float f; } lo, hi;
  lo.u = u << 16; hi.u = u & 0xffff0000u;
  f32x2 r; r.x = lo.f; r.y = hi.f; return r;
}
__device__ __forceinline__ float gelu_exact(float x){
  return 0.5f*x*(1.0f+erff(x*0.70710678118654752f));
}

// ================= prep: spectral kernel g + LN-folded bf16 weights =================
__device__ void fold_w(const float* __restrict__ W, int rows,
                       const float* __restrict__ lw, const float* __restrict__ lb,
                       u16* __restrict__ Wf, float* __restrict__ A, float* __restrict__ B){
  int tid = threadIdx.x;
  for (int e = tid; e < rows*64; e += 256) Wf[e] = f2bf(lw[e & 63] * W[e]);
  for (int r = tid; r < rows; r += 256){
    float a = 0.f, b2 = 0.f;
    for (int c = 0; c < 64; c++){ float w = W[r*64+c]; a += lw[c]*w; b2 += lb[c]*w; }
    A[r] = a; B[r] = b2;
  }
}

__global__ void k_prep(const float* __restrict__ M, float* __restrict__ g,
    const float* wq,  const float* l1iw, const float* l1ib, u16* wqf,  float* aq,  float* bq,
    const float* wkv, const float* l1ew, const float* l1eb, u16* wkvf, float* akv, float* bkv,
    const float* wpi, const float* l2w,  const float* l2b,  u16* wpif, float* api, float* bpi,
    const float* wpa, u16* wpaf, const float* wpf, u16* wpff)
{
  int blk = blockIdx.x, tid = threadIdx.x;
  if (blk < 64){
    int t = blk*256 + tid;           // < 256*64
    int c = t >> 6, uv = t & 63, u = uv >> 3, v = uv & 7;
    const float* mc = M + c*40;
    const float ctab[8] = {1.f, 0.70710678118654752f, 0.f, -0.70710678118654752f,
                           -1.f, -0.70710678118654752f, 0.f, 0.70710678118654752f};
    float acc = 0.f;
    for (int k1=0;k1<8;k1++)
      for (int k2=0;k2<8;k2++){
        float s = (k2<=4) ? mc[k1*5+k2] : mc[(((8-k1)&7)*5) + (8-k2)];
        acc += s * ctab[(k1*u + k2*v)&7];
      }
    g[t] = acc * (1.f/64.f);
  } else if (blk == 64){ fold_w(wq, 128, l1iw, l1ib, wqf, aq, bq); }
  else if (blk == 65){ fold_w(wkv, 256, l1ew, l1eb, wkvf, akv, bkv); }
  else if (blk == 66){ fold_w(wpi, 256, l2w, l2b, wpif, api, bpi); }
  else if (blk == 67){ for (int e=tid; e<64*128; e+=256) wpaf[e] = f2bf(wpa[e]); }
  else               { for (int e=tid; e<64*128; e+=256) wpff[e] = f2bf(wpf[e]); }
}

// ================= prep2: per-channel 64x64 circulant matrix from g (bf16) =================
__global__ void k_prep2(const float* __restrict__ g, u16* __restrict__ CM){
  int c = blockIdx.x;            // 256 channels
  const float* gc = g + (size_t)c*64;
  u16* cm = CM + (size_t)c*4096;
  for (int e = threadIdx.x; e < 4096; e += 256){
    int o = e >> 6, i = e & 63;
    int du = ((o>>3) - (i>>3)) & 7, dv = ((o&7) - (i&7)) & 7;
    cm[e] = f2bf(gc[du*8 + dv]);
  }
}

// ========== K=64 GEMM, 128 px/block, LN folded, stats via split-channel staging ==========
struct GA {
  const float* src; const u16* Wf; const float* Af; const float* Bf;
  u32* dst; int o0; int dstOffP; int Cdp; int b0; int pxbase;
};

template<int NZ>
__global__ __launch_bounds__(256) void k_gemm64(GA a0, GA a1){
  GA a = (blockIdx.y == 0) ? a0 : a1;
  __shared__ uint4 lsX[128*8];      // 16KB
  __shared__ uint4 lsW[64*NZ*8];    // 8/16/32KB
  __shared__ float2 sPart[256];     // 2KB
  __shared__ float2 sStat[128];     // 1KB
  int tid = threadIdx.x;
  int px = tid & 127, hf = tid >> 7;
  int p0 = a.pxbase + blockIdx.x*128;
  int b = p0 >> 16, hwb = p0 & 65535;
  {
    const uint4* wsrc = (const uint4*)(a.Wf + (size_t)a.o0*64);
    #pragma unroll
    for (int i=0; i<NZ*2; i++){
      int idx = i*256 + tid, row = idx>>3, s = idx&7;
      lsW[row*8 + (s ^ (row&7))] = wsrc[idx];
    }
  }
  {
    const float* sp = a.src + (size_t)b*64*HW + hwb + px + (size_t)(hf*32)*HW;
    float e[32];
    #pragma unroll
    for (int c=0;c<32;c++) e[c] = sp[(size_t)c*HW];
    float sm = 0.f, sq = 0.f;
    #pragma unroll
    for (int c=0;c<32;c++){ sm += e[c]; sq += e[c]*e[c]; }
    uint4* xrow = lsX + px*8;
    #pragma unroll
    for (int sl=0; sl<4; sl++){
      uint4 pkv;
      pkv.x = pk2(e[sl*8+0], e[sl*8+1]); pkv.y = pk2(e[sl*8+2], e[sl*8+3]);
      pkv.z = pk2(e[sl*8+4], e[sl*8+5]); pkv.w = pk2(e[sl*8+6], e[sl*8+7]);
      xrow[(hf*4+sl) ^ (px&7)] = pkv;
    }
    sPart[tid] = make_float2(sm, sq);
  }
  __syncthreads();
  if (tid < 128){
    float2 A = sPart[tid], B = sPart[tid+128];
    float s = A.x + B.x, q = A.y + B.y;
    float mu = s*(1.f/64.f);
    float var = q*(1.f/64.f) - mu*mu;
    sStat[tid] = make_float2(mu, rsqrtf(fmaxf(var,0.f)+1e-5f));
  }
  __syncthreads();
  int w = tid>>6, l = tid&63, g = l>>4, c15 = l&15;
  float2 stv[2];
  #pragma unroll
  for (int pp=0;pp<2;pp++) stv[pp] = sStat[w*32 + pp*16 + c15];

  #pragma unroll
  for (int z=0; z<NZ; z++){
    f32x4 acc[2][4];
    #pragma unroll
    for (int pp=0;pp<2;pp++)
      #pragma unroll
      for (int po=0;po<4;po++) acc[pp][po] = (f32x4){0.f,0.f,0.f,0.f};
    #pragma unroll
    for (int kk=0; kk<2; kk++){
      v8s wf[4], xf[2];
      #pragma unroll
      for (int po=0;po<4;po++){ int row = z*64 + po*16 + c15; wf[po] = as8(lsW[row*8 + ((kk*4+g) ^ (row&7))]); }
      #pragma unroll
      for (int pp=0;pp<2;pp++){ int row = w*32 + pp*16 + c15; xf[pp] = as8(lsX[row*8 + ((kk*4+g) ^ (row&7))]); }
      #pragma unroll
      for (int pp=0;pp<2;pp++)
        #pragma unroll
        for (int po=0;po<4;po++)
          acc[pp][po] = __builtin_amdgcn_mfma_f32_16x16x32_bf16(wf[po], xf[pp], acc[pp][po], 0,0,0);
    }
    size_t obaseP = ((size_t)(b - a.b0)*a.Cdp + a.dstOffP + z*32)*HW + hwb + w*32;
    #pragma unroll
    for (int po=0;po<4;po++)
      #pragma unroll
      for (int j2=0;j2<2;j2++){
        int oc = po*16 + g*4 + j2*2;
        float A0 = a.Af[a.o0 + z*64 + oc],   B0 = a.Bf[a.o0 + z*64 + oc];
        float A1 = a.Af[a.o0 + z*64 + oc+1], B1 = a.Bf[a.o0 + z*64 + oc+1];
        int ocp = po*8 + g*2 + j2;
        u32* dp = a.dst + obaseP + (size_t)ocp*HW + c15;
        #pragma unroll
        for (int pp=0;pp<2;pp++){
          float lo = stv[pp].y*(acc[pp][po][j2*2  ] - stv[pp].x*A0) + B0;
          float hi = stv[pp].y*(acc[pp][po][j2*2+1] - stv[pp].x*A1) + B1;
          dp[pp*16] = pk2(lo, hi);
        }
      }
  }
}

// ================= pair dw3x3 row-of-8 accumulate, packed f32x2 =================
__device__ __forceinline__ void dw8p_acc2(const u32* __restrict__ sp,
    const float* __restrict__ w9lo, const float* __restrict__ w9hi,
    int h, int w8, f32x2 a2[8])
{
  #pragma unroll
  for (int r=0;r<3;r++){
    int hh = h + r - 1;
    if (hh < 0 || hh > 255) continue;
    const u32* rp = sp + hh*256 + w8;
    uint4 ua = *(const uint4*)rp;
    uint4 ub = *(const uint4*)(rp+4);
    u32 e[8] = {ua.x,ua.y,ua.z,ua.w,ub.x,ub.y,ub.z,ub.w};
    u32 lef = (w8 > 0)   ? rp[-1] : 0u;
    u32 rig = (w8 < 248) ? rp[8]  : 0u;
    f32x2 vm[10];
    vm[0] = up2(lef);
    #pragma unroll
    for (int j=0;j<8;j++) vm[j+1] = up2(e[j]);
    vm[9] = up2(rig);
    f32x2 wa = {w9lo[r*3  ], w9hi[r*3  ]};
    f32x2 wb = {w9lo[r*3+1], w9hi[r*3+1]};
    f32x2 wc = {w9lo[r*3+2], w9hi[r*3+2]};
    #pragma unroll
    for (int j=0;j<8;j++)
      a2[j] += vm[j]*wa + vm[j+1]*wb + vm[j+2]*wc;
  }
}

// ================= FUSED: circqk (VALU-bound) || v-GEMM NZ=2 (memory-bound) =================
// grid 10240: bid%5==0 -> v-GEMM (gb = bid/5, 2048 blocks); else circqk (cq = bid-bid/5-1, 8192)
__global__ __launch_bounds__(256) void k_fused_cv(
    const u32* __restrict__ bq, const u32* __restrict__ bk,
    const float* __restrict__ dwq, const float* __restrict__ dwk,
    u32* __restrict__ orawp,
    const float* __restrict__ vsrc, const u16* __restrict__ Wf,
    const float* __restrict__ Af, const float* __restrict__ Bf,
    u32* __restrict__ vdst)
{
  __shared__ uint4 smemq[2304];   // 36864 B union
  int bid = blockIdx.x;
  int tid = threadIdx.x;
  if (bid % 5 == 0){
    // ---------- v GEMM body (NZ=2, o0=128) ----------
    int gb = bid / 5;
    uint4* lsX = smemq;                      // 128*8 uint4 = 16KB
    uint4* lsW = smemq + 1024;               // 128*8 uint4 = 16KB
    float2* sPart = (float2*)(smemq + 2048); // 2KB
    float2* sStat = (float2*)((char*)(smemq + 2048) + 2048); // 1KB
    int px = tid & 127, hf = tid >> 7;
    int p0 = gb*128;
    int b = p0 >> 16, hwb = p0 & 65535;
    {
      const uint4* wsrc = (const uint4*)(Wf + (size_t)128*64);
      #pragma unroll
      for (int i=0; i<4; i++){
        int idx = i*256 + tid, row = idx>>3, s = idx&7;
        lsW[row*8 + (s ^ (row&7))] = wsrc[idx];
      }
    }
    {
      const float* sp = vsrc + (size_t)b*64*HW + hwb + px + (size_t)(hf*32)*HW;
      float e[32];
      #pragma unroll
      for (int c=0;c<32;c++) e[c] = sp[(size_t)c*HW];
      float sm = 0.f, sq = 0.f;
      #pragma unroll
      for (int c=0;c<32;c++){ sm += e[c]; sq += e[c]*e[c]; }
      uint4* xrow = lsX + px*8;
      #pragma unroll
      for (int sl=0; sl<4; sl++){
        uint4 pkv;
        pkv.x = pk2(e[sl*8+0], e[sl*8+1]); pkv.y = pk2(e[sl*8+2], e[sl*8+3]);
        pkv.z = pk2(e[sl*8+4], e[sl*8+5]); pkv.w = pk2(e[sl*8+6], e[sl*8+7]);
        xrow[(hf*4+sl) ^ (px&7)] = pkv;
      }
      sPart[tid] = make_float2(sm, sq);
    }
    __syncthreads();
    if (tid < 128){
      float2 A = sPart[tid], B = sPart[tid+128];
      float s = A.x + B.x, q = A.y + B.y;
      float mu = s*(1.f/64.f);
      float var = q*(1.f/64.f) - mu*mu;
      sStat[tid] = make_float2(mu, rsqrtf(fmaxf(var,0.f)+1e-5f));
    }
    __syncthreads();
    int w = tid>>6, l = tid&63, g = l>>4, c15 = l&15;
    float2 stv[2];
    #pragma unroll
    for (int pp=0;pp<2;pp++) stv[pp] = sStat[w*32 + pp*16 + c15];
    #pragma unroll
    for (int z=0; z<2; z++){
      f32x4 acc[2][4];
      #pragma unroll
      for (int pp=0;pp<2;pp++)
        #pragma unroll
        for (int po=0;po<4;po++) acc[pp][po] = (f32x4){0.f,0.f,0.f,0.f};
      #pragma unroll
      for (int kk=0; kk<2; kk++){
        v8s wf[4], xf[2];
        #pragma unroll
        for (int po=0;po<4;po++){ int row = z*64 + po*16 + c15; wf[po] = as8(lsW[row*8 + ((kk*4+g) ^ (row&7))]); }
        #pragma unroll
        for (int pp=0;pp<2;pp++){ int row = w*32 + pp*16 + c15; xf[pp] = as8(lsX[row*8 + ((kk*4+g) ^ (row&7))]); }
        #pragma unroll
        for (int pp=0;pp<2;pp++)
          #pragma unroll
          for (int po=0;po<4;po++)
            acc[pp][po] = __builtin_amdgcn_mfma_f32_16x16x32_bf16(wf[po], xf[pp], acc[pp][po], 0,0,0);
      }
      size_t obaseP = ((size_t)b*64 + z*32)*HW + hwb + w*32;
      #pragma unroll
      for (int po=0;po<4;po++)
        #pragma unroll
        for (int j2=0;j2<2;j2++){
          int oc = po*16 + g*4 + j2*2;
          float A0 = Af[128 + z*64 + oc],   B0 = Bf[128 + z*64 + oc];
          float A1 = Af[128 + z*64 + oc+1], B1 = Bf[128 + z*64 + oc+1];
          int ocp = po*8 + g*2 + j2;
          u32* dp = vdst + obaseP + (size_t)ocp*HW + c15;
          #pragma unroll
          for (int pp=0;pp<2;pp++){
            float lo = stv[pp].y*(acc[pp][po][j2*2  ] - stv[pp].x*A0) + B0;
            float hi = stv[pp].y*(acc[pp][po][j2*2+1] - stv[pp].x*A1) + B1;
            dp[pp*16] = pk2(lo, hi);
          }
        }
    }
  } else {
    // ---------- circqk body ----------
    int cq = bid - bid/5 - 1;                 // 0..8191
    int strip = cq & 31, pr = (cq >> 5) & 63, b = cq >> 11;
    f32x2 (*qd)[288] = (f32x2(*)[288])smemq;                   // 18432 B
    f32x2 (*kd)[288] = (f32x2(*)[288])((char*)smemq + 18432);  // 18432 B
    int p = tid & 31, i = tid >> 5;
    int h0 = strip*8;
    const u32* qp = bq + ((size_t)(b*64+pr))*HW;
    const u32* kp = bk + ((size_t)(b*64+pr))*HW;
    const float* wq9 = dwq + (size_t)(2*pr)*9;
    const float* wk9 = dwk + (size_t)(2*pr)*9;
    {
      f32x2 a2[8];
      #pragma unroll
      for (int j=0;j<8;j++) a2[j] = (f32x2){0.f,0.f};
      dw8p_acc2(qp, wq9, wq9+9, h0+i, p*8, a2);
      #pragma unroll
      for (int j=0;j<8;j++) qd[i][p*9+j] = a2[j];
    }
    {
      f32x2 a2[8];
      #pragma unroll
      for (int j=0;j<8;j++) a2[j] = (f32x2){0.f,0.f};
      dw8p_acc2(kp, wk9, wk9+9, h0+i, p*8, a2);
      #pragma unroll
      for (int j=0;j<8;j++) kd[i][p*9+j] = a2[j];
    }
    __syncthreads();
    f32x2 o[8];
    #pragma unroll
    for (int j=0;j<8;j++) o[j] = (f32x2){0.f,0.f};
    #pragma unroll
    for (int u=0;u<8;u++){
      int ku = (i-u)&7;
      f32x2 qv[8], kr[8];
      #pragma unroll
      for (int v=0;v<8;v++) qv[v] = qd[u][p*9+v];
      #pragma unroll
      for (int e=0;e<8;e++) kr[e] = kd[ku][p*9+e];
      #pragma unroll
      for (int v=0;v<8;v++){
        f32x2 qq = qv[v];
        #pragma unroll
        for (int j=0;j<8;j++)
          o[j] += qq * kr[(j-v)&7];
      }
    }
    u32* op = orawp + ((size_t)(b*64 + pr))*HW + (size_t)(h0+i)*256 + p*8;
    uint4 s0, s1;
    s0.x=pk2(o[0].x,o[0].y); s0.y=pk2(o[1].x,o[1].y); s0.z=pk2(o[2].x,o[2].y); s0.w=pk2(o[3].x,o[3].y);
    s1.x=pk2(o[4].x,o[4].y); s1.y=pk2(o[5].x,o[5].y); s1.z=pk2(o[6].x,o[6].y); s1.w=pk2(o[7].x,o[7].y);
    *(uint4*)op = s0; *(uint4*)(op+4) = s1;
  }
}

// ================= attn epilogue GEMM (K=128): out = x + Wpo * (v .* LN128(oraw)) =================
__global__ __launch_bounds__(256) void k_gemm_attn(
    const float* __restrict__ x, const u32* __restrict__ orawp, const u32* __restrict__ vbp,
    const float* __restrict__ lnw, const float* __restrict__ lnb,
    const u16* __restrict__ Wf, float* __restrict__ out)
{
  __shared__ uint4 lsX[128*16];  // 32KB
  __shared__ uint4 lsW[64*16];   // 16KB
  __shared__ float2 sPart[256];
  __shared__ float2 sStat[128];
  int tid = threadIdx.x;
  int p0 = blockIdx.x*128;
  int b = p0 >> 16, hwb = p0 & 65535;
  int px = tid & 127, hf = tid >> 7;
  {
    const uint4* wsrc = (const uint4*)Wf;
    #pragma unroll
    for (int i=0;i<4;i++){
      int idx = i*256 + tid, row = idx>>4, s = idx&15;
      lsW[row*16 + (s ^ (row&15))] = wsrc[idx];
    }
  }
  const u32* orp = orawp + ((size_t)b*64 + hf*32)*HW + hwb + px;
  {
    u32 r32[32];
    #pragma unroll
    for (int i=0;i<32;i++) r32[i] = orp[(size_t)i*HW];
    float sum = 0.f, ssq = 0.f;
    #pragma unroll
    for (int sl=0; sl<8; sl++){
      u32 wds[4];
      #pragma unroll
      for (int q2=0;q2<4;q2++){
        u32 wv = r32[sl*4+q2];
        float fl = bf2f((u16)(wv&0xffff)), fh = bf2f((u16)(wv>>16));
        sum += fl + fh; ssq += fl*fl + fh*fh;
        wds[q2] = wv;
      }
      int s = hf*8 + sl;
      lsX[px*16 + (s ^ (px&15))] = make_uint4(wds[0],wds[1],wds[2],wds[3]);
    }
    sPart[tid] = make_float2(sum, ssq);
  }
  __syncthreads();
  if (tid < 128){
    float2 A = sPart[tid], B = sPart[tid+128];
    float s = A.x + B.x, q = A.y + B.y;
    float mu = s*(1.f/128.f);
    float var = q*(1.f/128.f) - mu*mu;
    sStat[tid] = make_float2(mu, rsqrtf(fmaxf(var,0.f)+1e-5f));
  }
  __syncthreads();
  {
    float2 st = sStat[px];
    const u32* vp = vbp + ((size_t)b*64 + hf*32)*HW + hwb + px;
    u32 v32[32];
    #pragma unroll
    for (int i=0;i<32;i++) v32[i] = vp[(size_t)i*HW];
    #pragma unroll
    for (int sl=0; sl<8; sl++){
      int s = hf*8 + sl;
      int li = px*16 + (s ^ (px&15));
      uint4 raw = lsX[li];
      u32 wds[4] = {raw.x, raw.y, raw.z, raw.w};
      u32 ow[4];
      #pragma unroll
      for (int q2=0;q2<4;q2++){
        int ch = hf*64 + sl*8 + q2*2;
        float e0 = bf2f((u16)(wds[q2]&0xffff)), e1 = bf2f((u16)(wds[q2]>>16));
        u32 vv = v32[sl*4+q2];
        float v0 = bf2f((u16)(vv&0xffff)), v1 = bf2f((u16)(vv>>16));
        float r0 = ((e0-st.x)*st.y*lnw[ch  ] + lnb[ch  ])*v0;
        float r1 = ((e1-st.x)*st.y*lnw[ch+1] + lnb[ch+1])*v1;
        ow[q2] = pk2(r0, r1);
      }
      lsX[li] = make_uint4(ow[0],ow[1],ow[2],ow[3]);
    }
  }
  __syncthreads();
  int w4 = tid>>6, l = tid&63, g = l>>4, c15 = l&15;
  f32x4 acc[2][4];
  #pragma unroll
  for (int pp=0;pp<2;pp++)
    #pragma unroll
    for (int po=0;po<4;po++) acc[pp][po] = (f32x4){0.f,0.f,0.f,0.f};
  #pragma unroll
  for (int kk=0; kk<4; kk++){
    v8s wf[4], xf[2];
    #pragma unroll
    for (int po=0;po<4;po++){ int row = po*16 + c15; wf[po] = as8(lsW[row*16 + ((kk*4+g) ^ (row&15))]); }
    #pragma unroll
    for (int pp=0;pp<2;pp++){ int row = w4*32 + pp*16 + c15; xf[pp] = as8(lsX[row*16 + ((kk*4+g) ^ (row&15))]); }
    #pragma unroll
    for (int pp=0;pp<2;pp++)
      #pragma unroll
      for (int po=0;po<4;po++)
        acc[pp][po] = __builtin_amdgcn_mfma_f32_16x16x32_bf16(wf[po], xf[pp], acc[pp][po], 0,0,0);
  }
  size_t obase = (size_t)b*64*HW + hwb + w4*32;
  #pragma unroll
  for (int po=0;po<4;po++)
    #pragma unroll
    for (int j=0;j<4;j++){
      int oc = po*16 + g*4 + j;
      const float* xs = x + obase + (size_t)oc*HW + c15;
      float* dp = out + obase + (size_t)oc*HW + c15;
      #pragma unroll
      for (int pp=0;pp<2;pp++) dp[pp*16] = xs[pp*16] + acc[pp][po][j];
    }
}

// ================= ffn epilogue GEMM (K=128): out += Wpo * y3g (pre-gated, pair-u32) =================
__global__ __launch_bounds__(256) void k_gemm_ffn(
    const u32* __restrict__ y3gp, const u16* __restrict__ Wf, float* __restrict__ out,
    int pxbase, int b0)
{
  __shared__ uint4 lsX[128*16];
  __shared__ uint4 lsW[64*16];
  int tid = threadIdx.x;
  int p0 = pxbase + blockIdx.x*128;
  int b = p0 >> 16, hwb = p0 & 65535;
  int px = tid & 127, hf = tid >> 7;
  {
    const uint4* wsrc = (const uint4*)Wf;
    #pragma unroll
    for (int i=0;i<4;i++){
      int idx = i*256 + tid, row = idx>>4, s = idx&15;
      lsW[row*16 + (s ^ (row&15))] = wsrc[idx];
    }
  }
  const u32* yp = y3gp + ((size_t)(b-b0)*64 + hf*32)*HW + hwb + px;
  {
    u32 r32[32];
    #pragma unroll
    for (int i=0;i<32;i++) r32[i] = yp[(size_t)i*HW];
    #pragma unroll
    for (int sl=0; sl<8; sl++){
      int s = hf*8 + sl;
      lsX[px*16 + (s ^ (px&15))] = make_uint4(r32[sl*4+0],r32[sl*4+1],r32[sl*4+2],r32[sl*4+3]);
    }
  }
  __syncthreads();
  int w4 = tid>>6, l = tid&63, g = l>>4, c15 = l&15;
  f32x4 acc[2][4];
  #pragma unroll
  for (int pp=0;pp<2;pp++)
    #pragma unroll
    for (int po=0;po<4;po++) acc[pp][po] = (f32x4){0.f,0.f,0.f,0.f};
  #pragma unroll
  for (int kk=0; kk<4; kk++){
    v8s wf[4], xf[2];
    #pragma unroll
    for (int po=0;po<4;po++){ int row = po*16 + c15; wf[po] = as8(lsW[row*16 + ((kk*4+g) ^ (row&15))]); }
    #pragma unroll
    for (int pp=0;pp<2;pp++){ int row = w4*32 + pp*16 + c15; xf[pp] = as8(lsX[row*16 + ((kk*4+g) ^ (row&15))]); }
    #pragma unroll
    for (int pp=0;pp<2;pp++)
      #pragma unroll
      for (int po=0;po<4;po++)
        acc[pp][po] = __builtin_amdgcn_mfma_f32_16x16x32_bf16(wf[po], xf[pp], acc[pp][po], 0,0,0);
  }
  size_t obase = (size_t)b*64*HW + hwb + w4*32;
  #pragma unroll
  for (int po=0;po<4;po++)
    #pragma unroll
    for (int j=0;j<4;j++){
      int oc = po*16 + g*4 + j;
      float* dp = out + obase + (size_t)oc*HW + c15;
      #pragma unroll
      for (int pp=0;pp<2;pp++) dp[pp*16] = dp[pp*16] + acc[pp][po][j];
    }
}

// ================= depthwise 3x3 pair (v path), parameterized source layout =================
__global__ __launch_bounds__(256) void k_dw8p(
    const u32* __restrict__ src, const float* __restrict__ wgt, int c0,
    u32* __restrict__ dstp, int dstOffP, int prMask, int prShift, int srcStride, int srcBase)
{
  int t = blockIdx.x*256 + threadIdx.x;
  int w8 = (t & 31)*8, h = (t>>5) & 255;
  int plane = t >> 13;
  int pr = plane & prMask, b = plane >> prShift;
  const u32* sp = src + ((size_t)(b*srcStride + srcBase + pr))*HW;
  const float* w9 = wgt + (size_t)(c0 + 2*pr)*9;
  f32x2 a2[8];
  #pragma unroll
  for (int j=0;j<8;j++) a2[j] = (f32x2){0.f,0.f};
  dw8p_acc2(sp, w9, w9+9, h, w8, a2);
  u32* dp = dstp + ((size_t)(b*64 + dstOffP + pr))*HW + h*256 + w8;
  uint4 s0, s1;
  s0.x=pk2(a2[0].x,a2[0].y); s0.y=pk2(a2[1].x,a2[1].y); s0.z=pk2(a2[2].x,a2[2].y); s0.w=pk2(a2[3].x,a2[3].y);
  s1.x=pk2(a2[4].x,a2[4].y); s1.y=pk2(a2[5].x,a2[5].y); s1.z=pk2(a2[6].x,a2[6].y); s1.w=pk2(a2[7].x,a2[7].y);
  *(uint4*)dp = s0; *(uint4*)(dp+4) = s1;
}

// ================= DFFN: pair dw3x3 on a & gate halves + GELU gate -> Y3Gp =================
__global__ __launch_bounds__(256) void k_dw8gp(
    const u32* __restrict__ Y0p, const float* __restrict__ wgt, u32* __restrict__ Y3gp)
{
  int t = blockIdx.x*256 + threadIdx.x;
  int w8 = (t & 31)*8, h = (t>>5) & 255;
  int pc = t >> 13;
  int pr = pc & 63, bl = pc >> 6;
  const u32* spA = Y0p + ((size_t)(bl*128 + pr))*HW;
  const u32* spG = Y0p + ((size_t)(bl*128 + 64 + pr))*HW;
  const float* w9a = wgt + (size_t)(2*pr)*9;
  const float* w9g = wgt + (size_t)(128 + 2*pr)*9;
  f32x2 aA[8], aG[8];
  #pragma unroll
  for (int j=0;j<8;j++){ aA[j] = (f32x2){0.f,0.f}; aG[j] = (f32x2){0.f,0.f}; }
  dw8p_acc2(spA, w9a, w9a+9, h, w8, aA);
  dw8p_acc2(spG, w9g, w9g+9, h, w8, aG);
  u32* dp = Y3gp + ((size_t)(bl*64 + pr))*HW + h*256 + w8;
  uint4 s0, s1;
  s0.x=pk2(gelu_exact(aA[0].x)*aG[0].x, gelu_exact(aA[0].y)*aG[0].y);
  s0.y=pk2(gelu_exact(aA[1].x)*aG[1].x, gelu_exact(aA[1].y)*aG[1].y);
  s0.z=pk2(gelu_exact(aA[2].x)*aG[2].x, gelu_exact(aA[2].y)*aG[2].y);
  s0.w=pk2(gelu_exact(aA[3].x)*aG[3].x, gelu_exact(aA[3].y)*aG[3].y);
  s1.x=pk2(gelu_exact(aA[4].x)*aG[4].x, gelu_exact(aA[4].y)*aG[4].y);
  s1.y=pk2(gelu_exact(aA[5].x)*aG[5].x, gelu_exact(aA[5].y)*aG[5].y);
  s1.z=pk2(gelu_exact(aA[6].x)*aG[6].x, gelu_exact(aA[6].y)*aG[6].y);
  s1.w=pk2(gelu_exact(aA[7].x)*aG[7].x, gelu_exact(aA[7].y)*aG[7].y);
  *(uint4*)dp = s0; *(uint4*)(dp+4) = s1;
}

// ================= standalone circqk (fallback path) =================
__global__ __launch_bounds__(256) void k_circqk4(
    const u32* __restrict__ bq, const u32* __restrict__ bk,
    const float* __restrict__ dwq, const float* __restrict__ dwk, int c0,
    u32* __restrict__ orawp, int oprBase, int cpbq, int cpbk)
{
  __shared__ f32x2 qd[8][288];
  __shared__ f32x2 kd[8][288];
  int tid = threadIdx.x;
  int p = tid & 31, i = tid >> 5;
  int pr = blockIdx.y, b = blockIdx.z;
  int h0 = blockIdx.x*8;
  const u32* qp = bq + ((size_t)(b*cpbq+pr))*HW;
  const u32* kp = bk + ((size_t)(b*cpbk+pr))*HW;
  const float* wq9 = dwq + (size_t)(c0 + 2*pr)*9;
  const float* wk9 = dwk + (size_t)(c0 + 2*pr)*9;
  {
    f32x2 a2[8];
    #pragma unroll
    for (int j=0;j<8;j++) a2[j] = (f32x2){0.f,0.f};
    dw8p_acc2(qp, wq9, wq9+9, h0+i, p*8, a2);
    #pragma unroll
    for (int j=0;j<8;j++) qd[i][p*9+j] = a2[j];
  }
  {
    f32x2 a2[8];
    #pragma unroll
    for (int j=0;j<8;j++) a2[j] = (f32x2){0.f,0.f};
    dw8p_acc2(kp, wk9, wk9+9, h0+i, p*8, a2);
    #pragma unroll
    for (int j=0;j<8;j++) kd[i][p*9+j] = a2[j];
  }
  __syncthreads();
  f32x2 o[8];
  #pragma unroll
  for (int j=0;j<8;j++) o[j] = (f32x2){0.f,0.f};
  #pragma unroll
  for (int u=0;u<8;u++){
    int ku = (i-u)&7;
    f32x2 qv[8], kr[8];
    #pragma unroll
    for (int v=0;v<8;v++) qv[v] = qd[u][p*9+v];
    #pragma unroll
    for (int e=0;e<8;e++) kr[e] = kd[ku][p*9+e];
    #pragma unroll
    for (int v=0;v<8;v++){
      f32x2 qq = qv[v];
      #pragma unroll
      for (int j=0;j<8;j++)
        o[j] += qq * kr[(j-v)&7];
    }
  }
  u32* op = orawp + ((size_t)(b*64 + oprBase + pr))*HW + (size_t)(h0+i)*256 + p*8;
  uint4 s0, s1;
  s0.x=pk2(o[0].x,o[0].y); s0.y=pk2(o[1].x,o[1].y); s0.z=pk2(o[2].x,o[2].y); s0.w=pk2(o[3].x,o[3].y);
  s1.x=pk2(o[4].x,o[4].y); s1.y=pk2(o[5].x,o[5].y); s1.z=pk2(o[6].x,o[6].y); s1.w=pk2(o[7].x,o[7].y);
  *(uint4*)op = s0; *(uint4*)(op+4) = s1;
}

// ================= DFFN spectral circ conv as per-channel 64x64 GEMM (MFMA), in-place =================
__global__ __launch_bounds__(256) void k_circg_mfma(
    u32* __restrict__ y, const u16* __restrict__ CM)
{
  __shared__ uint4 lsA[2][64*8];
  __shared__ uint4 lsB[2][64*8];
  int tid = threadIdx.x;
  int pr = blockIdx.y, b = blockIdx.z;
  int h0 = blockIdx.x*16;
  u32* plane = y + ((size_t)(b*128+pr))*HW;
  {
    const uint4* cmsrc = (const uint4*)(CM + (size_t)(2*pr)*4096);
    #pragma unroll
    for (int t=0; t<4; t++){
      int idx = t*256 + tid;
      int ch = idx >> 9, e = idx & 511;
      int row = e >> 3, s = e & 7;
      lsA[ch][row*8 + (s ^ (row&7))] = cmsrc[ch*512 + e];
    }
  }
  {
    #pragma unroll
    for (int t=0; t<2; t++){
      int rr = t*256 + tid;
      int n = rr >> 3, i = rr & 7;
      const u32* rp = plane + (size_t)(h0 + (n>>5)*8 + i)*256 + (n&31)*8;
      uint4 ua = *(const uint4*)rp;
      uint4 ub = *(const uint4*)(rp+4);
      u32 e[8] = {ua.x,ua.y,ua.z,ua.w,ub.x,ub.y,ub.z,ub.w};
      uint4 L, H;
      L.x = (e[0]&0xffffu) | (e[1]<<16);
      L.y = (e[2]&0xffffu) | (e[3]<<16);
      L.z = (e[4]&0xffffu) | (e[5]<<16);
      L.w = (e[6]&0xffffu) | (e[7]<<16);
      H.x = (e[0]>>16) | (e[1]&0xffff0000u);
      H.y = (e[2]>>16) | (e[3]&0xffff0000u);
      H.z = (e[4]>>16) | (e[5]&0xffff0000u);
      H.w = (e[6]>>16) | (e[7]&0xffff0000u);
      lsB[0][n*8 + (i ^ (n&7))] = L;
      lsB[1][n*8 + (i ^ (n&7))] = H;
    }
  }
  __syncthreads();
  int w = tid>>6, l = tid&63, g = l>>4, c15 = l&15;
  f32x4 acc[2][4];
  #pragma unroll
  for (int ch=0;ch<2;ch++)
    #pragma unroll
    for (int po=0;po<4;po++) acc[ch][po] = (f32x4){0.f,0.f,0.f,0.f};
  #pragma unroll
  for (int kk=0; kk<2; kk++){
    v8s bfr[2];
    { int row = w*16 + c15;
      bfr[0] = as8(lsB[0][row*8 + ((kk*4+g) ^ (row&7))]);
      bfr[1] = as8(lsB[1][row*8 + ((kk*4+g) ^ (row&7))]); }
    #pragma unroll
    for (int po=0;po<4;po++){
      int row = po*16 + c15;
      v8s aL = as8(lsA[0][row*8 + ((kk*4+g) ^ (row&7))]);
      v8s aH = as8(lsA[1][row*8 + ((kk*4+g) ^ (row&7))]);
      acc[0][po] = __builtin_amdgcn_mfma_f32_16x16x32_bf16(aL, bfr[0], acc[0][po], 0,0,0);
      acc[1][po] = __builtin_amdgcn_mfma_f32_16x16x32_bf16(aH, bfr[1], acc[1][po], 0,0,0);
    }
  }
  int patch = w*16 + c15;
  u32* pbase = plane + (size_t)(h0 + (patch>>5)*8)*256 + (patch&31)*8;
  #pragma unroll
  for (int po=0;po<4;po++){
    int oh = po*2 + (g>>1), ow4 = 4*(g&1);
    uint4 sv;
    sv.x = pk2(acc[0][po][0], acc[1][po][0]);
    sv.y = pk2(acc[0][po][1], acc[1][po][1]);
    sv.z = pk2(acc[0][po][2], acc[1][po][2]);
    sv.w = pk2(acc[0][po][3], acc[1][po][3]);
    *(uint4*)(pbase + (size_t)oh*256 + ow4) = sv;
  }
}

extern "C" void kernel_launch(void* const* d_in, const int* in_sizes, int n_in,
                              void* d_out, int out_size, void* d_ws, size_t ws_size,
                              hipStream_t stream)
{
  const float* x       = (const float*)d_in[0];
  const float* evt     = (const float*)d_in[1];
  const float* ln1i_w  = (const float*)d_in[2];
  const float* ln1i_b  = (const float*)d_in[3];
  const float* ln1e_w  = (const float*)d_in[4];
  const float* ln1e_b  = (const float*)d_in[5];
  const float* w_q     = (const float*)d_in[6];
  const float* dw_q    = (const float*)d_in[7];
  const float* w_kv    = (const float*)d_in[8];
  const float* dw_kv   = (const float*)d_in[9];
  const float* lnA_w   = (const float*)d_in[10];
  const float* lnA_b   = (const float*)d_in[11];
  const float* w_po_at = (const float*)d_in[12];
  const float* ln2_w   = (const float*)d_in[13];
  const float* ln2_b   = (const float*)d_in[14];
  const float* w_pi    = (const float*)d_in[15];
  const float* fft_par = (const float*)d_in[16];
  const float* dw_ffn  = (const float*)d_in[17];
  const float* w_poffn = (const float*)d_in[18];
  float* out = (float*)d_out;

  char* ws = (char*)d_ws;
  const size_t MiB = 1048576ull;
  bool big = (ws_size >= 200*MiB);
  size_t smOff = big ? 192*MiB : 160*MiB;
  char* sm = ws + smOff;
  float* G    = (float*)(sm);                   // 64 KiB
  u16* WQF    = (u16*)(sm + 65536);
  u16* WKVF   = (u16*)(sm + 81920);
  u16* WPIF   = (u16*)(sm + 114688);
  u16* WPAF   = (u16*)(sm + 147456);
  u16* WPFF   = (u16*)(sm + 163840);
  float* AQ   = (float*)(sm + 180224);
  float* BQ   = (float*)(sm + 180736);
  float* AKV  = (float*)(sm + 181248);
  float* BKV  = (float*)(sm + 182272);
  float* API  = (float*)(sm + 183296);
  float* BPI  = (float*)(sm + 184320);
  u16* CMAT   = (u16*)(sm + 1*MiB);             // 2 MiB

  dim3 blk256(256);

  k_prep<<<69, blk256, 0, stream>>>(fft_par, G,
      w_q, ln1i_w, ln1i_b, WQF, AQ, BQ,
      w_kv, ln1e_w, ln1e_b, WKVF, AKV, BKV,
      w_pi, ln2_w, ln2_b, WPIF, API, BPI,
      w_po_at, WPAF, w_poffn, WPFF);
  k_prep2<<<256, blk256, 0, stream>>>(G, CMAT);

  if (big){
    // layout: QBUF 0..64 | KBUF 64..128 | ORAW 128..192 | sm 192+. PV staged in d_out.
    u32* QBUF  = (u32*)(ws);
    u32* KBUF  = (u32*)(ws + 64*MiB);
    u32* ORAWp = (u32*)(ws + 128*MiB);
    u32* VBUFp = (u32*)(ws);             // over QBUF (dead after fused launch)
    u32* Y0p   = (u32*)(ws);             // 128 MiB over QBUF+KBUF (dead after attn)
    u32* Y3Gp  = (u32*)(ws + 128*MiB);   // 64 MiB over ORAW (dead after attn)
    u32* PV    = (u32*)out;              // v-GEMM staging in d_out (dead until attn writes)

    GA qa = {x,   WQF,  AQ,  BQ,  QBUF, 0, 0, 64, 0, 0};
    GA ka = {evt, WKVF, AKV, BKV, KBUF, 0, 0, 64, 0, 0};
    k_gemm64<2><<<dim3(2048,2,1), blk256, 0, stream>>>(qa, ka);
    // fused: circqk (8192 blocks) || v-GEMM -> PV=d_out (2048 blocks), interleaved 4:1
    k_fused_cv<<<10240, blk256, 0, stream>>>(QBUF, KBUF, dw_q, dw_kv, ORAWp,
                                             evt, WKVF, AKV, BKV, PV);
    k_dw8p<<<8192, blk256, 0, stream>>>(PV, dw_kv, 128, VBUFp, 0, 63, 6, 64, 0);
    k_gemm_attn<<<2048, blk256, 0, stream>>>(x, ORAWp, VBUFp, lnA_w, lnA_b, WPAF, out);
    // ---- DFFN merged over all 4 batches ----
    GA pa = {out, WPIF, API, BPI, Y0p, 0, 0, 128, 0, 0};
    k_gemm64<4><<<dim3(2048,1,1), blk256, 0, stream>>>(pa, pa);
    k_circg_mfma<<<dim3(16,128,4), blk256, 0, stream>>>(Y0p, CMAT);
    k_dw8gp<<<8192, blk256, 0, stream>>>(Y0p, dw_ffn, Y3Gp);
    k_gemm_ffn<<<2048, blk256, 0, stream>>>(Y3Gp, WPFF, out, 0, 0);
  } else {
    // fallback: chunked layout (peak 163 MiB, proven)
    u32* P1p   = (u32*)(ws);
    u32* ORAWp = (u32*)(ws + 32*MiB);
    u32* P2p   = (u32*)(ws + 96*MiB);
    u32* VBUFp = (u32*)(ws + 96*MiB);
    u32* Y0p   = (u32*)(ws);
    u32* Y3Gp  = (u32*)(ws + 64*MiB);

    for (int i=0;i<2;i++){
      GA qa = {x,   WQF,  AQ,  BQ,  P1p, 64*i, 0, 32, 0, 0};
      GA ka = {evt, WKVF, AKV, BKV, P2p, 64*i, 0, 32, 0, 0};
      k_gemm64<1><<<dim3(2048,2,1), blk256, 0, stream>>>(qa, ka);
      k_circqk4<<<dim3(32,32,4), blk256, 0, stream>>>(P1p, P2p, dw_q, dw_kv, 64*i, ORAWp, 32*i, 32, 32);
    }
    for (int i=0;i<2;i++){
      GA va = {evt, WKVF, AKV, BKV, P1p, 128+64*i, 0, 32, 0, 0};
      k_gemm64<1><<<dim3(2048,1,1), blk256, 0, stream>>>(va, va);
      k_dw8p<<<4096, blk256, 0, stream>>>(P1p, dw_kv, 128+64*i, VBUFp, 32*i, 31, 5, 32, 0);
    }
    k_gemm_attn<<<2048, blk256, 0, stream>>>(x, ORAWp, VBUFp, lnA_w, lnA_b, WPAF, out);
    for (int h=0;h<2;h++){
      GA pa = {out, WPIF, API, BPI, Y0p, 0, 0, 128, 2*h, h*131072};
      k_gemm64<4><<<dim3(1024,1,1), blk256, 0, stream>>>(pa, pa);
      k_circg_mfma<<<dim3(16,128,2), blk256, 0, stream>>>(Y0p, CMAT);
      k_dw8gp<<<4096, blk256, 0, stream>>>(Y0p, dw_ffn, Y3Gp);
      k_gemm_ffn<<<1024, blk256, 0, stream>>>(Y3Gp, WPFF, out, h*131072, 2*h);
    }
  }
}

// Round 22
// 464.223 us; speedup vs baseline: 1.0975x; 1.0975x over previous
//
#include <hip/hip_runtime.h>

#define HW 65536          // 256*256
#define NPOS 262144       // B(4) * HW

typedef unsigned int   u32;
typedef unsigned short u16;
typedef __attribute__((ext_vector_type(8))) short v8s;
typedef __attribute__((ext_vector_type(4))) float f32x4;
typedef __attribute__((ext_vector_type(2))) float f32x2;

__device__ __forceinline__ float bf2f(u16 h){
  union { u32 u; float f; } c; c.u = ((u32)h) << 16; return c.f;
}
__device__ __forceinline__ u16 f2bf(float f){
  union { u32 u; float f; } c; c.f = f;
  u32 r = c.u + 0x7fffu + ((c.u >> 16) & 1u);
  return (u16)(r >> 16);
}
__device__ __forceinline__ u32 pk2(float a, float b){
  return (u32)f2bf(a) | ((u32)f2bf(b) << 16);
}
__device__ __forceinline__ v8s as8(uint4 u){
  union { uint4 a; v8s b; } c; c.a = u; return c.b;
}
__device__ __forceinline__ f32x2 up2(u32 u){
  union { u32 u; float f; } lo, hi;
  lo.u = u << 16; hi.u = u & 0xffff0000u;
  f32x2 r; r.x = lo.f; r.y = hi.f; return r;
}
__device__ __forceinline__ float gelu_exact(float x){
  return 0.5f*x*(1.0f+erff(x*0.70710678118654752f));
}

// ================= prep: spectral kernel g + LN-folded bf16 weights =================
__device__ void fold_w(const float* __restrict__ W, int rows,
                       const float* __restrict__ lw, const float* __restrict__ lb,
                       u16* __restrict__ Wf, float* __restrict__ A, float* __restrict__ B){
  int tid = threadIdx.x;
  for (int e = tid; e < rows*64; e += 256) Wf[e] = f2bf(lw[e & 63] * W[e]);
  for (int r = tid; r < rows; r += 256){
    float a = 0.f, b2 = 0.f;
    for (int c = 0; c < 64; c++){ float w = W[r*64+c]; a += lw[c]*w; b2 += lb[c]*w; }
    A[r] = a; B[r] = b2;
  }
}

__global__ void k_prep(const float* __restrict__ M, float* __restrict__ g,
    const float* wq,  const float* l1iw, const float* l1ib, u16* wqf,  float* aq,  float* bq,
    const float* wkv, const float* l1ew, const float* l1eb, u16* wkvf, float* akv, float* bkv,
    const float* wpi, const float* l2w,  const float* l2b,  u16* wpif, float* api, float* bpi,
    const float* wpa, u16* wpaf, const float* wpf, u16* wpff)
{
  int blk = blockIdx.x, tid = threadIdx.x;
  if (blk < 64){
    int t = blk*256 + tid;           // < 256*64
    int c = t >> 6, uv = t & 63, u = uv >> 3, v = uv & 7;
    const float* mc = M + c*40;
    const float ctab[8] = {1.f, 0.70710678118654752f, 0.f, -0.70710678118654752f,
                           -1.f, -0.70710678118654752f, 0.f, 0.70710678118654752f};
    float acc = 0.f;
    for (int k1=0;k1<8;k1++)
      for (int k2=0;k2<8;k2++){
        float s = (k2<=4) ? mc[k1*5+k2] : mc[(((8-k1)&7)*5) + (8-k2)];
        acc += s * ctab[(k1*u + k2*v)&7];
      }
    g[t] = acc * (1.f/64.f);
  } else if (blk == 64){ fold_w(wq, 128, l1iw, l1ib, wqf, aq, bq); }
  else if (blk == 65){ fold_w(wkv, 256, l1ew, l1eb, wkvf, akv, bkv); }
  else if (blk == 66){ fold_w(wpi, 256, l2w, l2b, wpif, api, bpi); }
  else if (blk == 67){ for (int e=tid; e<64*128; e+=256) wpaf[e] = f2bf(wpa[e]); }
  else               { for (int e=tid; e<64*128; e+=256) wpff[e] = f2bf(wpf[e]); }
}

// ================= prep2: per-channel 64x64 circulant matrix from g (bf16) =================
__global__ void k_prep2(const float* __restrict__ g, u16* __restrict__ CM){
  int c = blockIdx.x;            // 256 channels
  const float* gc = g + (size_t)c*64;
  u16* cm = CM + (size_t)c*4096;
  for (int e = threadIdx.x; e < 4096; e += 256){
    int o = e >> 6, i = e & 63;
    int du = ((o>>3) - (i>>3)) & 7, dv = ((o&7) - (i&7)) & 7;
    cm[e] = f2bf(gc[du*8 + dv]);
  }
}

// ========== K=64 GEMM, 128 px/block, LN folded, stats via split-channel staging ==========
struct GA {
  const float* src; const u16* Wf; const float* Af; const float* Bf;
  u32* dst; int o0; int dstOffP; int Cdp; int b0; int pxbase;
};

template<int NZ>
__global__ __launch_bounds__(256) void k_gemm64(GA a0, GA a1){
  GA a = (blockIdx.y == 0) ? a0 : a1;
  __shared__ uint4 lsX[128*8];      // 16KB
  __shared__ uint4 lsW[64*NZ*8];    // 8/16/32KB
  __shared__ float2 sPart[256];     // 2KB
  __shared__ float2 sStat[128];     // 1KB
  int tid = threadIdx.x;
  int px = tid & 127, hf = tid >> 7;
  int p0 = a.pxbase + blockIdx.x*128;
  int b = p0 >> 16, hwb = p0 & 65535;
  {
    const uint4* wsrc = (const uint4*)(a.Wf + (size_t)a.o0*64);
    #pragma unroll
    for (int i=0; i<NZ*2; i++){
      int idx = i*256 + tid, row = idx>>3, s = idx&7;
      lsW[row*8 + (s ^ (row&7))] = wsrc[idx];
    }
  }
  {
    const float* sp = a.src + (size_t)b*64*HW + hwb + px + (size_t)(hf*32)*HW;
    float e[32];
    #pragma unroll
    for (int c=0;c<32;c++) e[c] = sp[(size_t)c*HW];
    float sm = 0.f, sq = 0.f;
    #pragma unroll
    for (int c=0;c<32;c++){ sm += e[c]; sq += e[c]*e[c]; }
    uint4* xrow = lsX + px*8;
    #pragma unroll
    for (int sl=0; sl<4; sl++){
      uint4 pkv;
      pkv.x = pk2(e[sl*8+0], e[sl*8+1]); pkv.y = pk2(e[sl*8+2], e[sl*8+3]);
      pkv.z = pk2(e[sl*8+4], e[sl*8+5]); pkv.w = pk2(e[sl*8+6], e[sl*8+7]);
      xrow[(hf*4+sl) ^ (px&7)] = pkv;
    }
    sPart[tid] = make_float2(sm, sq);
  }
  __syncthreads();
  if (tid < 128){
    float2 A = sPart[tid], B = sPart[tid+128];
    float s = A.x + B.x, q = A.y + B.y;
    float mu = s*(1.f/64.f);
    float var = q*(1.f/64.f) - mu*mu;
    sStat[tid] = make_float2(mu, rsqrtf(fmaxf(var,0.f)+1e-5f));
  }
  __syncthreads();
  int w = tid>>6, l = tid&63, g = l>>4, c15 = l&15;
  float2 stv[2];
  #pragma unroll
  for (int pp=0;pp<2;pp++) stv[pp] = sStat[w*32 + pp*16 + c15];

  #pragma unroll
  for (int z=0; z<NZ; z++){
    f32x4 acc[2][4];
    #pragma unroll
    for (int pp=0;pp<2;pp++)
      #pragma unroll
      for (int po=0;po<4;po++) acc[pp][po] = (f32x4){0.f,0.f,0.f,0.f};
    #pragma unroll
    for (int kk=0; kk<2; kk++){
      v8s wf[4], xf[2];
      #pragma unroll
      for (int po=0;po<4;po++){ int row = z*64 + po*16 + c15; wf[po] = as8(lsW[row*8 + ((kk*4+g) ^ (row&7))]); }
      #pragma unroll
      for (int pp=0;pp<2;pp++){ int row = w*32 + pp*16 + c15; xf[pp] = as8(lsX[row*8 + ((kk*4+g) ^ (row&7))]); }
      #pragma unroll
      for (int pp=0;pp<2;pp++)
        #pragma unroll
        for (int po=0;po<4;po++)
          acc[pp][po] = __builtin_amdgcn_mfma_f32_16x16x32_bf16(wf[po], xf[pp], acc[pp][po], 0,0,0);
    }
    size_t obaseP = ((size_t)(b - a.b0)*a.Cdp + a.dstOffP + z*32)*HW + hwb + w*32;
    #pragma unroll
    for (int po=0;po<4;po++)
      #pragma unroll
      for (int j2=0;j2<2;j2++){
        int oc = po*16 + g*4 + j2*2;
        float A0 = a.Af[a.o0 + z*64 + oc],   B0 = a.Bf[a.o0 + z*64 + oc];
        float A1 = a.Af[a.o0 + z*64 + oc+1], B1 = a.Bf[a.o0 + z*64 + oc+1];
        int ocp = po*8 + g*2 + j2;
        u32* dp = a.dst + obaseP + (size_t)ocp*HW + c15;
        #pragma unroll
        for (int pp=0;pp<2;pp++){
          float lo = stv[pp].y*(acc[pp][po][j2*2  ] - stv[pp].x*A0) + B0;
          float hi = stv[pp].y*(acc[pp][po][j2*2+1] - stv[pp].x*A1) + B1;
          dp[pp*16] = pk2(lo, hi);
        }
      }
  }
}

// ================= attn epilogue GEMM (K=128): out = x + Wpo * (v .* LN128(oraw)) =================
__global__ __launch_bounds__(256) void k_gemm_attn(
    const float* __restrict__ x, const u32* __restrict__ orawp, const u32* __restrict__ vbp,
    const float* __restrict__ lnw, const float* __restrict__ lnb,
    const u16* __restrict__ Wf, float* __restrict__ out)
{
  __shared__ uint4 lsX[128*16];  // 32KB
  __shared__ uint4 lsW[64*16];   // 16KB
  __shared__ float2 sPart[256];
  __shared__ float2 sStat[128];
  int tid = threadIdx.x;
  int p0 = blockIdx.x*128;
  int b = p0 >> 16, hwb = p0 & 65535;
  int px = tid & 127, hf = tid >> 7;
  {
    const uint4* wsrc = (const uint4*)Wf;
    #pragma unroll
    for (int i=0;i<4;i++){
      int idx = i*256 + tid, row = idx>>4, s = idx&15;
      lsW[row*16 + (s ^ (row&15))] = wsrc[idx];
    }
  }
  const u32* orp = orawp + ((size_t)b*64 + hf*32)*HW + hwb + px;
  {
    u32 r32[32];
    #pragma unroll
    for (int i=0;i<32;i++) r32[i] = orp[(size_t)i*HW];
    float sum = 0.f, ssq = 0.f;
    #pragma unroll
    for (int sl=0; sl<8; sl++){
      u32 wds[4];
      #pragma unroll
      for (int q2=0;q2<4;q2++){
        u32 wv = r32[sl*4+q2];
        float fl = bf2f((u16)(wv&0xffff)), fh = bf2f((u16)(wv>>16));
        sum += fl + fh; ssq += fl*fl + fh*fh;
        wds[q2] = wv;
      }
      int s = hf*8 + sl;
      lsX[px*16 + (s ^ (px&15))] = make_uint4(wds[0],wds[1],wds[2],wds[3]);
    }
    sPart[tid] = make_float2(sum, ssq);
  }
  __syncthreads();
  if (tid < 128){
    float2 A = sPart[tid], B = sPart[tid+128];
    float s = A.x + B.x, q = A.y + B.y;
    float mu = s*(1.f/128.f);
    float var = q*(1.f/128.f) - mu*mu;
    sStat[tid] = make_float2(mu, rsqrtf(fmaxf(var,0.f)+1e-5f));
  }
  __syncthreads();
  {
    float2 st = sStat[px];
    const u32* vp = vbp + ((size_t)b*64 + hf*32)*HW + hwb + px;
    u32 v32[32];
    #pragma unroll
    for (int i=0;i<32;i++) v32[i] = vp[(size_t)i*HW];
    #pragma unroll
    for (int sl=0; sl<8; sl++){
      int s = hf*8 + sl;
      int li = px*16 + (s ^ (px&15));
      uint4 raw = lsX[li];
      u32 wds[4] = {raw.x, raw.y, raw.z, raw.w};
      u32 ow[4];
      #pragma unroll
      for (int q2=0;q2<4;q2++){
        int ch = hf*64 + sl*8 + q2*2;
        float e0 = bf2f((u16)(wds[q2]&0xffff)), e1 = bf2f((u16)(wds[q2]>>16));
        u32 vv = v32[sl*4+q2];
        float v0 = bf2f((u16)(vv&0xffff)), v1 = bf2f((u16)(vv>>16));
        float r0 = ((e0-st.x)*st.y*lnw[ch  ] + lnb[ch  ])*v0;
        float r1 = ((e1-st.x)*st.y*lnw[ch+1] + lnb[ch+1])*v1;
        ow[q2] = pk2(r0, r1);
      }
      lsX[li] = make_uint4(ow[0],ow[1],ow[2],ow[3]);
    }
  }
  __syncthreads();
  int w4 = tid>>6, l = tid&63, g = l>>4, c15 = l&15;
  f32x4 acc[2][4];
  #pragma unroll
  for (int pp=0;pp<2;pp++)
    #pragma unroll
    for (int po=0;po<4;po++) acc[pp][po] = (f32x4){0.f,0.f,0.f,0.f};
  #pragma unroll
  for (int kk=0; kk<4; kk++){
    v8s wf[4], xf[2];
    #pragma unroll
    for (int po=0;po<4;po++){ int row = po*16 + c15; wf[po] = as8(lsW[row*16 + ((kk*4+g) ^ (row&15))]); }
    #pragma unroll
    for (int pp=0;pp<2;pp++){ int row = w4*32 + pp*16 + c15; xf[pp] = as8(lsX[row*16 + ((kk*4+g) ^ (row&15))]); }
    #pragma unroll
    for (int pp=0;pp<2;pp++)
      #pragma unroll
      for (int po=0;po<4;po++)
        acc[pp][po] = __builtin_amdgcn_mfma_f32_16x16x32_bf16(wf[po], xf[pp], acc[pp][po], 0,0,0);
  }
  size_t obase = (size_t)b*64*HW + hwb + w4*32;
  #pragma unroll
  for (int po=0;po<4;po++)
    #pragma unroll
    for (int j=0;j<4;j++){
      int oc = po*16 + g*4 + j;
      const float* xs = x + obase + (size_t)oc*HW + c15;
      float* dp = out + obase + (size_t)oc*HW + c15;
      #pragma unroll
      for (int pp=0;pp<2;pp++) dp[pp*16] = xs[pp*16] + acc[pp][po][j];
    }
}

// ================= ffn epilogue GEMM (K=128): out += Wpo * y3g (pre-gated, pair-u32) =================
__global__ __launch_bounds__(256) void k_gemm_ffn(
    const u32* __restrict__ y3gp, const u16* __restrict__ Wf, float* __restrict__ out,
    int pxbase, int b0)
{
  __shared__ uint4 lsX[128*16];
  __shared__ uint4 lsW[64*16];
  int tid = threadIdx.x;
  int p0 = pxbase + blockIdx.x*128;
  int b = p0 >> 16, hwb = p0 & 65535;
  int px = tid & 127, hf = tid >> 7;
  {
    const uint4* wsrc = (const uint4*)Wf;
    #pragma unroll
    for (int i=0;i<4;i++){
      int idx = i*256 + tid, row = idx>>4, s = idx&15;
      lsW[row*16 + (s ^ (row&15))] = wsrc[idx];
    }
  }
  const u32* yp = y3gp + ((size_t)(b-b0)*64 + hf*32)*HW + hwb + px;
  {
    u32 r32[32];
    #pragma unroll
    for (int i=0;i<32;i++) r32[i] = yp[(size_t)i*HW];
    #pragma unroll
    for (int sl=0; sl<8; sl++){
      int s = hf*8 + sl;
      lsX[px*16 + (s ^ (px&15))] = make_uint4(r32[sl*4+0],r32[sl*4+1],r32[sl*4+2],r32[sl*4+3]);
    }
  }
  __syncthreads();
  int w4 = tid>>6, l = tid&63, g = l>>4, c15 = l&15;
  f32x4 acc[2][4];
  #pragma unroll
  for (int pp=0;pp<2;pp++)
    #pragma unroll
    for (int po=0;po<4;po++) acc[pp][po] = (f32x4){0.f,0.f,0.f,0.f};
  #pragma unroll
  for (int kk=0; kk<4; kk++){
    v8s wf[4], xf[2];
    #pragma unroll
    for (int po=0;po<4;po++){ int row = po*16 + c15; wf[po] = as8(lsW[row*16 + ((kk*4+g) ^ (row&15))]); }
    #pragma unroll
    for (int pp=0;pp<2;pp++){ int row = w4*32 + pp*16 + c15; xf[pp] = as8(lsX[row*16 + ((kk*4+g) ^ (row&15))]); }
    #pragma unroll
    for (int pp=0;pp<2;pp++)
      #pragma unroll
      for (int po=0;po<4;po++)
        acc[pp][po] = __builtin_amdgcn_mfma_f32_16x16x32_bf16(wf[po], xf[pp], acc[pp][po], 0,0,0);
  }
  size_t obase = (size_t)b*64*HW + hwb + w4*32;
  #pragma unroll
  for (int po=0;po<4;po++)
    #pragma unroll
    for (int j=0;j<4;j++){
      int oc = po*16 + g*4 + j;
      float* dp = out + obase + (size_t)oc*HW + c15;
      #pragma unroll
      for (int pp=0;pp<2;pp++) dp[pp*16] = dp[pp*16] + acc[pp][po][j];
    }
}

// ================= pair dw3x3 row-of-8 accumulate, packed f32x2 =================
__device__ __forceinline__ void dw8p_acc2(const u32* __restrict__ sp,
    const float* __restrict__ w9lo, const float* __restrict__ w9hi,
    int h, int w8, f32x2 a2[8])
{
  #pragma unroll
  for (int r=0;r<3;r++){
    int hh = h + r - 1;
    if (hh < 0 || hh > 255) continue;
    const u32* rp = sp + hh*256 + w8;
    uint4 ua = *(const uint4*)rp;
    uint4 ub = *(const uint4*)(rp+4);
    u32 e[8] = {ua.x,ua.y,ua.z,ua.w,ub.x,ub.y,ub.z,ub.w};
    u32 lef = (w8 > 0)   ? rp[-1] : 0u;
    u32 rig = (w8 < 248) ? rp[8]  : 0u;
    f32x2 vm[10];
    vm[0] = up2(lef);
    #pragma unroll
    for (int j=0;j<8;j++) vm[j+1] = up2(e[j]);
    vm[9] = up2(rig);
    f32x2 wa = {w9lo[r*3  ], w9hi[r*3  ]};
    f32x2 wb = {w9lo[r*3+1], w9hi[r*3+1]};
    f32x2 wc = {w9lo[r*3+2], w9hi[r*3+2]};
    #pragma unroll
    for (int j=0;j<8;j++)
      a2[j] += vm[j]*wa + vm[j+1]*wb + vm[j+2]*wc;
  }
}

// ================= depthwise 3x3 pair (v path), parameterized source layout =================
__global__ __launch_bounds__(256) void k_dw8p(
    const u32* __restrict__ src, const float* __restrict__ wgt, int c0,
    u32* __restrict__ dstp, int dstOffP, int prMask, int prShift, int srcStride, int srcBase)
{
  int t = blockIdx.x*256 + threadIdx.x;
  int w8 = (t & 31)*8, h = (t>>5) & 255;
  int plane = t >> 13;
  int pr = plane & prMask, b = plane >> prShift;
  const u32* sp = src + ((size_t)(b*srcStride + srcBase + pr))*HW;
  const float* w9 = wgt + (size_t)(c0 + 2*pr)*9;
  f32x2 a2[8];
  #pragma unroll
  for (int j=0;j<8;j++) a2[j] = (f32x2){0.f,0.f};
  dw8p_acc2(sp, w9, w9+9, h, w8, a2);
  u32* dp = dstp + ((size_t)(b*64 + dstOffP + pr))*HW + h*256 + w8;
  uint4 s0, s1;
  s0.x=pk2(a2[0].x,a2[0].y); s0.y=pk2(a2[1].x,a2[1].y); s0.z=pk2(a2[2].x,a2[2].y); s0.w=pk2(a2[3].x,a2[3].y);
  s1.x=pk2(a2[4].x,a2[4].y); s1.y=pk2(a2[5].x,a2[5].y); s1.z=pk2(a2[6].x,a2[6].y); s1.w=pk2(a2[7].x,a2[7].y);
  *(uint4*)dp = s0; *(uint4*)(dp+4) = s1;
}

// ================= DFFN: pair dw3x3 on a & gate halves + GELU gate -> Y3Gp =================
__global__ __launch_bounds__(256) void k_dw8gp(
    const u32* __restrict__ Y0p, const float* __restrict__ wgt, u32* __restrict__ Y3gp)
{
  int t = blockIdx.x*256 + threadIdx.x;
  int w8 = (t & 31)*8, h = (t>>5) & 255;
  int pc = t >> 13;
  int pr = pc & 63, bl = pc >> 6;
  const u32* spA = Y0p + ((size_t)(bl*128 + pr))*HW;
  const u32* spG = Y0p + ((size_t)(bl*128 + 64 + pr))*HW;
  const float* w9a = wgt + (size_t)(2*pr)*9;
  const float* w9g = wgt + (size_t)(128 + 2*pr)*9;
  f32x2 aA[8], aG[8];
  #pragma unroll
  for (int j=0;j<8;j++){ aA[j] = (f32x2){0.f,0.f}; aG[j] = (f32x2){0.f,0.f}; }
  dw8p_acc2(spA, w9a, w9a+9, h, w8, aA);
  dw8p_acc2(spG, w9g, w9g+9, h, w8, aG);
  u32* dp = Y3gp + ((size_t)(bl*64 + pr))*HW + h*256 + w8;
  uint4 s0, s1;
  s0.x=pk2(gelu_exact(aA[0].x)*aG[0].x, gelu_exact(aA[0].y)*aG[0].y);
  s0.y=pk2(gelu_exact(aA[1].x)*aG[1].x, gelu_exact(aA[1].y)*aG[1].y);
  s0.z=pk2(gelu_exact(aA[2].x)*aG[2].x, gelu_exact(aA[2].y)*aG[2].y);
  s0.w=pk2(gelu_exact(aA[3].x)*aG[3].x, gelu_exact(aA[3].y)*aG[3].y);
  s1.x=pk2(gelu_exact(aA[4].x)*aG[4].x, gelu_exact(aA[4].y)*aG[4].y);
  s1.y=pk2(gelu_exact(aA[5].x)*aG[5].x, gelu_exact(aA[5].y)*aG[5].y);
  s1.z=pk2(gelu_exact(aA[6].x)*aG[6].x, gelu_exact(aA[6].y)*aG[6].y);
  s1.w=pk2(gelu_exact(aA[7].x)*aG[7].x, gelu_exact(aA[7].y)*aG[7].y);
  *(uint4*)dp = s0; *(uint4*)(dp+4) = s1;
}

// ================= fused dw(q), dw(k) + per-patch circular conv, f32x2 LDS (best) ====
__global__ __launch_bounds__(256) void k_circqk4(
    const u32* __restrict__ bq, const u32* __restrict__ bk,
    const float* __restrict__ dwq, const float* __restrict__ dwk, int c0,
    u32* __restrict__ orawp, int oprBase, int cpb)
{
  __shared__ f32x2 qd[8][288];
  __shared__ f32x2 kd[8][288];
  int tid = threadIdx.x;
  int p = tid & 31, i = tid >> 5;
  int pr = blockIdx.y, b = blockIdx.z;
  int h0 = blockIdx.x*8;
  const u32* qp = bq + ((size_t)(b*cpb+pr))*HW;
  const u32* kp = bk + ((size_t)(b*cpb+pr))*HW;
  const float* wq9 = dwq + (size_t)(c0 + 2*pr)*9;
  const float* wk9 = dwk + (size_t)(c0 + 2*pr)*9;
  {
    f32x2 a2[8];
    #pragma unroll
    for (int j=0;j<8;j++) a2[j] = (f32x2){0.f,0.f};
    dw8p_acc2(qp, wq9, wq9+9, h0+i, p*8, a2);
    #pragma unroll
    for (int j=0;j<8;j++) qd[i][p*9+j] = a2[j];
  }
  {
    f32x2 a2[8];
    #pragma unroll
    for (int j=0;j<8;j++) a2[j] = (f32x2){0.f,0.f};
    dw8p_acc2(kp, wk9, wk9+9, h0+i, p*8, a2);
    #pragma unroll
    for (int j=0;j<8;j++) kd[i][p*9+j] = a2[j];
  }
  __syncthreads();
  f32x2 o[8];
  #pragma unroll
  for (int j=0;j<8;j++) o[j] = (f32x2){0.f,0.f};
  #pragma unroll
  for (int u=0;u<8;u++){
    int ku = (i-u)&7;
    f32x2 qv[8], kr[8];
    #pragma unroll
    for (int v=0;v<8;v++) qv[v] = qd[u][p*9+v];
    #pragma unroll
    for (int e=0;e<8;e++) kr[e] = kd[ku][p*9+e];
    #pragma unroll
    for (int v=0;v<8;v++){
      f32x2 qq = qv[v];
      #pragma unroll
      for (int j=0;j<8;j++)
        o[j] += qq * kr[(j-v)&7];
    }
  }
  u32* op = orawp + ((size_t)(b*64 + oprBase + pr))*HW + (size_t)(h0+i)*256 + p*8;
  uint4 s0, s1;
  s0.x=pk2(o[0].x,o[0].y); s0.y=pk2(o[1].x,o[1].y); s0.z=pk2(o[2].x,o[2].y); s0.w=pk2(o[3].x,o[3].y);
  s1.x=pk2(o[4].x,o[4].y); s1.y=pk2(o[5].x,o[5].y); s1.z=pk2(o[6].x,o[6].y); s1.w=pk2(o[7].x,o[7].y);
  *(uint4*)op = s0; *(uint4*)(op+4) = s1;
}

// ================= DFFN spectral circ conv as per-channel 64x64 GEMM (MFMA), in-place =================
__global__ __launch_bounds__(256) void k_circg_mfma(
    u32* __restrict__ y, const u16* __restrict__ CM)
{
  __shared__ uint4 lsA[2][64*8];
  __shared__ uint4 lsB[2][64*8];
  int tid = threadIdx.x;
  int pr = blockIdx.y, b = blockIdx.z;
  int h0 = blockIdx.x*16;
  u32* plane = y + ((size_t)(b*128+pr))*HW;
  {
    const uint4* cmsrc = (const uint4*)(CM + (size_t)(2*pr)*4096);
    #pragma unroll
    for (int t=0; t<4; t++){
      int idx = t*256 + tid;
      int ch = idx >> 9, e = idx & 511;
      int row = e >> 3, s = e & 7;
      lsA[ch][row*8 + (s ^ (row&7))] = cmsrc[ch*512 + e];
    }
  }
  {
    #pragma unroll
    for (int t=0; t<2; t++){
      int rr = t*256 + tid;
      int n = rr >> 3, i = rr & 7;
      const u32* rp = plane + (size_t)(h0 + (n>>5)*8 + i)*256 + (n&31)*8;
      uint4 ua = *(const uint4*)rp;
      uint4 ub = *(const uint4*)(rp+4);
      u32 e[8] = {ua.x,ua.y,ua.z,ua.w,ub.x,ub.y,ub.z,ub.w};
      uint4 L, H;
      L.x = (e[0]&0xffffu) | (e[1]<<16);
      L.y = (e[2]&0xffffu) | (e[3]<<16);
      L.z = (e[4]&0xffffu) | (e[5]<<16);
      L.w = (e[6]&0xffffu) | (e[7]<<16);
      H.x = (e[0]>>16) | (e[1]&0xffff0000u);
      H.y = (e[2]>>16) | (e[3]&0xffff0000u);
      H.z = (e[4]>>16) | (e[5]&0xffff0000u);
      H.w = (e[6]>>16) | (e[7]&0xffff0000u);
      lsB[0][n*8 + (i ^ (n&7))] = L;
      lsB[1][n*8 + (i ^ (n&7))] = H;
    }
  }
  __syncthreads();
  int w = tid>>6, l = tid&63, g = l>>4, c15 = l&15;
  f32x4 acc[2][4];
  #pragma unroll
  for (int ch=0;ch<2;ch++)
    #pragma unroll
    for (int po=0;po<4;po++) acc[ch][po] = (f32x4){0.f,0.f,0.f,0.f};
  #pragma unroll
  for (int kk=0; kk<2; kk++){
    v8s bfr[2];
    { int row = w*16 + c15;
      bfr[0] = as8(lsB[0][row*8 + ((kk*4+g) ^ (row&7))]);
      bfr[1] = as8(lsB[1][row*8 + ((kk*4+g) ^ (row&7))]); }
    #pragma unroll
    for (int po=0;po<4;po++){
      int row = po*16 + c15;
      v8s aL = as8(lsA[0][row*8 + ((kk*4+g) ^ (row&7))]);
      v8s aH = as8(lsA[1][row*8 + ((kk*4+g) ^ (row&7))]);
      acc[0][po] = __builtin_amdgcn_mfma_f32_16x16x32_bf16(aL, bfr[0], acc[0][po], 0,0,0);
      acc[1][po] = __builtin_amdgcn_mfma_f32_16x16x32_bf16(aH, bfr[1], acc[1][po], 0,0,0);
    }
  }
  int patch = w*16 + c15;
  u32* pbase = plane + (size_t)(h0 + (patch>>5)*8)*256 + (patch&31)*8;
  #pragma unroll
  for (int po=0;po<4;po++){
    int oh = po*2 + (g>>1), ow4 = 4*(g&1);
    uint4 sv;
    sv.x = pk2(acc[0][po][0], acc[1][po][0]);
    sv.y = pk2(acc[0][po][1], acc[1][po][1]);
    sv.z = pk2(acc[0][po][2], acc[1][po][2]);
    sv.w = pk2(acc[0][po][3], acc[1][po][3]);
    *(uint4*)(pbase + (size_t)oh*256 + ow4) = sv;
  }
}

extern "C" void kernel_launch(void* const* d_in, const int* in_sizes, int n_in,
                              void* d_out, int out_size, void* d_ws, size_t ws_size,
                              hipStream_t stream)
{
  const float* x       = (const float*)d_in[0];
  const float* evt     = (const float*)d_in[1];
  const float* ln1i_w  = (const float*)d_in[2];
  const float* ln1i_b  = (const float*)d_in[3];
  const float* ln1e_w  = (const float*)d_in[4];
  const float* ln1e_b  = (const float*)d_in[5];
  const float* w_q     = (const float*)d_in[6];
  const float* dw_q    = (const float*)d_in[7];
  const float* w_kv    = (const float*)d_in[8];
  const float* dw_kv   = (const float*)d_in[9];
  const float* lnA_w   = (const float*)d_in[10];
  const float* lnA_b   = (const float*)d_in[11];
  const float* w_po_at = (const float*)d_in[12];
  const float* ln2_w   = (const float*)d_in[13];
  const float* ln2_b   = (const float*)d_in[14];
  const float* w_pi    = (const float*)d_in[15];
  const float* fft_par = (const float*)d_in[16];
  const float* dw_ffn  = (const float*)d_in[17];
  const float* w_poffn = (const float*)d_in[18];
  float* out = (float*)d_out;

  char* ws = (char*)d_ws;
  const size_t MiB = 1048576ull;
  bool big = (ws_size >= 200*MiB);
  size_t smOff = big ? 192*MiB : 160*MiB;
  char* sm = ws + smOff;
  float* G    = (float*)(sm);                   // 64 KiB
  u16* WQF    = (u16*)(sm + 65536);
  u16* WKVF   = (u16*)(sm + 81920);
  u16* WPIF   = (u16*)(sm + 114688);
  u16* WPAF   = (u16*)(sm + 147456);
  u16* WPFF   = (u16*)(sm + 163840);
  float* AQ   = (float*)(sm + 180224);
  float* BQ   = (float*)(sm + 180736);
  float* AKV  = (float*)(sm + 181248);
  float* BKV  = (float*)(sm + 182272);
  float* API  = (float*)(sm + 183296);
  float* BPI  = (float*)(sm + 184320);
  u16* CMAT   = (u16*)(sm + 1*MiB);             // 2 MiB

  dim3 blk256(256);

  k_prep<<<69, blk256, 0, stream>>>(fft_par, G,
      w_q, ln1i_w, ln1i_b, WQF, AQ, BQ,
      w_kv, ln1e_w, ln1e_b, WKVF, AKV, BKV,
      w_pi, ln2_w, ln2_b, WPIF, API, BPI,
      w_po_at, WPAF, w_poffn, WPFF);
  k_prep2<<<256, blk256, 0, stream>>>(G, CMAT);

  if (big){
    // merged layout: QBUF 0..64, KBUF 64..128, ORAW 128..192 (MiB)
    u32* QBUF  = (u32*)(ws);
    u32* KBUF  = (u32*)(ws + 64*MiB);
    u32* ORAWp = (u32*)(ws + 128*MiB);
    u32* PV    = (u32*)(ws + 64*MiB);    // over KBUF (dead after circqk)
    u32* VBUFp = (u32*)(ws);             // over QBUF (dead after circqk)
    u32* Y0p   = (u32*)(ws);             // (4,128,HW) u32 = 128 MiB, over QBUF+KBUF (dead after attn)
    u32* Y3Gp  = (u32*)(ws + 128*MiB);   // (4,64,HW) u32 = 64 MiB, over ORAW (dead after attn)

    GA qa = {x,   WQF,  AQ,  BQ,  QBUF, 0, 0, 64, 0, 0};
    GA ka = {evt, WKVF, AKV, BKV, KBUF, 0, 0, 64, 0, 0};
    k_gemm64<2><<<dim3(2048,2,1), blk256, 0, stream>>>(qa, ka);
    k_circqk4<<<dim3(32,64,4), blk256, 0, stream>>>(QBUF, KBUF, dw_q, dw_kv, 0, ORAWp, 0, 64);
    GA va = {evt, WKVF, AKV, BKV, PV, 128, 0, 64, 0, 0};
    k_gemm64<2><<<dim3(2048,1,1), blk256, 0, stream>>>(va, va);
    k_dw8p<<<8192, blk256, 0, stream>>>(PV, dw_kv, 128, VBUFp, 0, 63, 6, 64, 0);
    k_gemm_attn<<<2048, blk256, 0, stream>>>(x, ORAWp, VBUFp, lnA_w, lnA_b, WPAF, out);
    // ---- DFFN merged over all 4 batches ----
    GA pa = {out, WPIF, API, BPI, Y0p, 0, 0, 128, 0, 0};
    k_gemm64<4><<<dim3(2048,1,1), blk256, 0, stream>>>(pa, pa);
    k_circg_mfma<<<dim3(16,128,4), blk256, 0, stream>>>(Y0p, CMAT);
    k_dw8gp<<<8192, blk256, 0, stream>>>(Y0p, dw_ffn, Y3Gp);
    k_gemm_ffn<<<2048, blk256, 0, stream>>>(Y3Gp, WPFF, out, 0, 0);
  } else {
    // fallback: chunked layout (peak 163 MiB, proven)
    u32* P1p   = (u32*)(ws);
    u32* ORAWp = (u32*)(ws + 32*MiB);
    u32* P2p   = (u32*)(ws + 96*MiB);
    u32* VBUFp = (u32*)(ws + 96*MiB);
    u32* Y0p   = (u32*)(ws);
    u32* Y3Gp  = (u32*)(ws + 64*MiB);

    for (int i=0;i<2;i++){
      GA qa = {x,   WQF,  AQ,  BQ,  P1p, 64*i, 0, 32, 0, 0};
      GA ka = {evt, WKVF, AKV, BKV, P2p, 64*i, 0, 32, 0, 0};
      k_gemm64<1><<<dim3(2048,2,1), blk256, 0, stream>>>(qa, ka);
      k_circqk4<<<dim3(32,32,4), blk256, 0, stream>>>(P1p, P2p, dw_q, dw_kv, 64*i, ORAWp, 32*i, 32);
    }
    for (int i=0;i<2;i++){
      GA va = {evt, WKVF, AKV, BKV, P1p, 128+64*i, 0, 32, 0, 0};
      k_gemm64<1><<<dim3(2048,1,1), blk256, 0, stream>>>(va, va);
      k_dw8p<<<4096, blk256, 0, stream>>>(P1p, dw_kv, 128+64*i, VBUFp, 32*i, 31, 5, 32, 0);
    }
    k_gemm_attn<<<2048, blk256, 0, stream>>>(x, ORAWp, VBUFp, lnA_w, lnA_b, WPAF, out);
    for (int h=0;h<2;h++){
      GA pa = {out, WPIF, API, BPI, Y0p, 0, 0, 128, 2*h, h*131072};
      k_gemm64<4><<<dim3(1024,1,1), blk256, 0, stream>>>(pa, pa);
      k_circg_mfma<<<dim3(16,128,2), blk256, 0, stream>>>(Y0p, CMAT);
      k_dw8gp<<<4096, blk256, 0, stream>>>(Y0p, dw_ffn, Y3Gp);
      k_gemm_ffn<<<1024, blk256, 0, stream>>>(Y3Gp, WPFF, out, h*131072, 2*h);
    }
  }
}

// Round 23
// 449.676 us; speedup vs baseline: 1.1330x; 1.0324x over previous
//
#include <hip/hip_runtime.h>

#define HW 65536          // 256*256
#define NPOS 262144       // B(4) * HW

typedef unsigned int   u32;
typedef unsigned short u16;
typedef __attribute__((ext_vector_type(8))) short v8s;
typedef __attribute__((ext_vector_type(4))) float f32x4;
typedef __attribute__((ext_vector_type(2))) float f32x2;

__device__ __forceinline__ float bf2f(u16 h){
  union { u32 u; float f; } c; c.u = ((u32)h) << 16; return c.f;
}
__device__ __forceinline__ u16 f2bf(float f){
  union { u32 u; float f; } c; c.f = f;
  u32 r = c.u + 0x7fffu + ((c.u >> 16) & 1u);
  return (u16)(r >> 16);
}
__device__ __forceinline__ u32 pk2(float a, float b){
  return (u32)f2bf(a) | ((u32)f2bf(b) << 16);
}
__device__ __forceinline__ v8s as8(uint4 u){
  union { uint4 a; v8s b; } c; c.a = u; return c.b;
}
__device__ __forceinline__ f32x2 up2(u32 u){
  union { u32 u; float f; } lo, hi;
  lo.u = u << 16; hi.u = u & 0xffff0000u;
  f32x2 r; r.x = lo.f; r.y = hi.f; return r;
}
__device__ __forceinline__ float gelu_exact(float x){
  return 0.5f*x*(1.0f+erff(x*0.70710678118654752f));
}

// ================= prep: spectral kernel g + LN-folded bf16 weights =================
__device__ void fold_w(const float* __restrict__ W, int rows,
                       const float* __restrict__ lw, const float* __restrict__ lb,
                       u16* __restrict__ Wf, float* __restrict__ A, float* __restrict__ B){
  int tid = threadIdx.x;
  for (int e = tid; e < rows*64; e += 256) Wf[e] = f2bf(lw[e & 63] * W[e]);
  for (int r = tid; r < rows; r += 256){
    float a = 0.f, b2 = 0.f;
    for (int c = 0; c < 64; c++){ float w = W[r*64+c]; a += lw[c]*w; b2 += lb[c]*w; }
    A[r] = a; B[r] = b2;
  }
}

__global__ void k_prep(const float* __restrict__ M, float* __restrict__ g,
    const float* wq,  const float* l1iw, const float* l1ib, u16* wqf,  float* aq,  float* bq,
    const float* wkv, const float* l1ew, const float* l1eb, u16* wkvf, float* akv, float* bkv,
    const float* wpi, const float* l2w,  const float* l2b,  u16* wpif, float* api, float* bpi,
    const float* wpa, u16* wpaf, const float* wpf, u16* wpff)
{
  int blk = blockIdx.x, tid = threadIdx.x;
  if (blk < 64){
    int t = blk*256 + tid;           // < 256*64
    int c = t >> 6, uv = t & 63, u = uv >> 3, v = uv & 7;
    const float* mc = M + c*40;
    const float ctab[8] = {1.f, 0.70710678118654752f, 0.f, -0.70710678118654752f,
                           -1.f, -0.70710678118654752f, 0.f, 0.70710678118654752f};
    float acc = 0.f;
    for (int k1=0;k1<8;k1++)
      for (int k2=0;k2<8;k2++){
        float s = (k2<=4) ? mc[k1*5+k2] : mc[(((8-k1)&7)*5) + (8-k2)];
        acc += s * ctab[(k1*u + k2*v)&7];
      }
    g[t] = acc * (1.f/64.f);
  } else if (blk == 64){ fold_w(wq, 128, l1iw, l1ib, wqf, aq, bq); }
  else if (blk == 65){ fold_w(wkv, 256, l1ew, l1eb, wkvf, akv, bkv); }
  else if (blk == 66){ fold_w(wpi, 256, l2w, l2b, wpif, api, bpi); }
  else if (blk == 67){ for (int e=tid; e<64*128; e+=256) wpaf[e] = f2bf(wpa[e]); }
  else               { for (int e=tid; e<64*128; e+=256) wpff[e] = f2bf(wpf[e]); }
}

// ================= prep2: per-channel 64x64 circulant matrix from g (bf16) =================
__global__ void k_prep2(const float* __restrict__ g, u16* __restrict__ CM){
  int c = blockIdx.x;            // 256 channels
  const float* gc = g + (size_t)c*64;
  u16* cm = CM + (size_t)c*4096;
  for (int e = threadIdx.x; e < 4096; e += 256){
    int o = e >> 6, i = e & 63;
    int du = ((o>>3) - (i>>3)) & 7, dv = ((o&7) - (i&7)) & 7;
    cm[e] = f2bf(gc[du*8 + dv]);
  }
}

// ========== K=64 GEMM, 128 px/block, LN folded, stats via split-channel staging ==========
struct GA {
  const float* src; const u16* Wf; const float* Af; const float* Bf;
  u32* dst; int o0; int dstOffP; int Cdp; int b0; int pxbase;
};

template<int NZ>
__global__ __launch_bounds__(256) void k_gemm64(GA a0, GA a1){
  GA a = (blockIdx.y == 0) ? a0 : a1;
  __shared__ uint4 lsX[128*8];      // 16KB
  __shared__ uint4 lsW[64*NZ*8];    // 8/16/32KB
  __shared__ float2 sPart[256];     // 2KB
  __shared__ float2 sStat[128];     // 1KB
  int tid = threadIdx.x;
  int px = tid & 127, hf = tid >> 7;
  int p0 = a.pxbase + blockIdx.x*128;
  int b = p0 >> 16, hwb = p0 & 65535;
  {
    const uint4* wsrc = (const uint4*)(a.Wf + (size_t)a.o0*64);
    #pragma unroll
    for (int i=0; i<NZ*2; i++){
      int idx = i*256 + tid, row = idx>>3, s = idx&7;
      lsW[row*8 + (s ^ (row&7))] = wsrc[idx];
    }
  }
  {
    const float* sp = a.src + (size_t)b*64*HW + hwb + px + (size_t)(hf*32)*HW;
    float e[32];
    #pragma unroll
    for (int c=0;c<32;c++) e[c] = sp[(size_t)c*HW];
    float sm = 0.f, sq = 0.f;
    #pragma unroll
    for (int c=0;c<32;c++){ sm += e[c]; sq += e[c]*e[c]; }
    uint4* xrow = lsX + px*8;
    #pragma unroll
    for (int sl=0; sl<4; sl++){
      uint4 pkv;
      pkv.x = pk2(e[sl*8+0], e[sl*8+1]); pkv.y = pk2(e[sl*8+2], e[sl*8+3]);
      pkv.z = pk2(e[sl*8+4], e[sl*8+5]); pkv.w = pk2(e[sl*8+6], e[sl*8+7]);
      xrow[(hf*4+sl) ^ (px&7)] = pkv;
    }
    sPart[tid] = make_float2(sm, sq);
  }
  __syncthreads();
  if (tid < 128){
    float2 A = sPart[tid], B = sPart[tid+128];
    float s = A.x + B.x, q = A.y + B.y;
    float mu = s*(1.f/64.f);
    float var = q*(1.f/64.f) - mu*mu;
    sStat[tid] = make_float2(mu, rsqrtf(fmaxf(var,0.f)+1e-5f));
  }
  __syncthreads();
  int w = tid>>6, l = tid&63, g = l>>4, c15 = l&15;
  float2 stv[2];
  #pragma unroll
  for (int pp=0;pp<2;pp++) stv[pp] = sStat[w*32 + pp*16 + c15];

  #pragma unroll
  for (int z=0; z<NZ; z++){
    f32x4 acc[2][4];
    #pragma unroll
    for (int pp=0;pp<2;pp++)
      #pragma unroll
      for (int po=0;po<4;po++) acc[pp][po] = (f32x4){0.f,0.f,0.f,0.f};
    #pragma unroll
    for (int kk=0; kk<2; kk++){
      v8s wf[4], xf[2];
      #pragma unroll
      for (int po=0;po<4;po++){ int row = z*64 + po*16 + c15; wf[po] = as8(lsW[row*8 + ((kk*4+g) ^ (row&7))]); }
      #pragma unroll
      for (int pp=0;pp<2;pp++){ int row = w*32 + pp*16 + c15; xf[pp] = as8(lsX[row*8 + ((kk*4+g) ^ (row&7))]); }
      #pragma unroll
      for (int pp=0;pp<2;pp++)
        #pragma unroll
        for (int po=0;po<4;po++)
          acc[pp][po] = __builtin_amdgcn_mfma_f32_16x16x32_bf16(wf[po], xf[pp], acc[pp][po], 0,0,0);
    }
    size_t obaseP = ((size_t)(b - a.b0)*a.Cdp + a.dstOffP + z*32)*HW + hwb + w*32;
    #pragma unroll
    for (int po=0;po<4;po++)
      #pragma unroll
      for (int j2=0;j2<2;j2++){
        int oc = po*16 + g*4 + j2*2;
        float A0 = a.Af[a.o0 + z*64 + oc],   B0 = a.Bf[a.o0 + z*64 + oc];
        float A1 = a.Af[a.o0 + z*64 + oc+1], B1 = a.Bf[a.o0 + z*64 + oc+1];
        int ocp = po*8 + g*2 + j2;
        u32* dp = a.dst + obaseP + (size_t)ocp*HW + c15;
        #pragma unroll
        for (int pp=0;pp<2;pp++){
          float lo = stv[pp].y*(acc[pp][po][j2*2  ] - stv[pp].x*A0) + B0;
          float hi = stv[pp].y*(acc[pp][po][j2*2+1] - stv[pp].x*A1) + B1;
          dp[pp*16] = pk2(lo, hi);
        }
      }
  }
}

// ================= attn epilogue GEMM (K=128): out = x + Wpo * (v .* LN128(oraw)) =================
__global__ __launch_bounds__(256) void k_gemm_attn(
    const float* __restrict__ x, const u32* __restrict__ orawp, const u32* __restrict__ vbp,
    const float* __restrict__ lnw, const float* __restrict__ lnb,
    const u16* __restrict__ Wf, float* __restrict__ out)
{
  __shared__ uint4 lsX[128*16];  // 32KB
  __shared__ uint4 lsW[64*16];   // 16KB
  __shared__ float2 sPart[256];
  __shared__ float2 sStat[128];
  int tid = threadIdx.x;
  int p0 = blockIdx.x*128;
  int b = p0 >> 16, hwb = p0 & 65535;
  int px = tid & 127, hf = tid >> 7;
  {
    const uint4* wsrc = (const uint4*)Wf;
    #pragma unroll
    for (int i=0;i<4;i++){
      int idx = i*256 + tid, row = idx>>4, s = idx&15;
      lsW[row*16 + (s ^ (row&15))] = wsrc[idx];
    }
  }
  const u32* orp = orawp + ((size_t)b*64 + hf*32)*HW + hwb + px;
  {
    u32 r32[32];
    #pragma unroll
    for (int i=0;i<32;i++) r32[i] = orp[(size_t)i*HW];
    float sum = 0.f, ssq = 0.f;
    #pragma unroll
    for (int sl=0; sl<8; sl++){
      u32 wds[4];
      #pragma unroll
      for (int q2=0;q2<4;q2++){
        u32 wv = r32[sl*4+q2];
        float fl = bf2f((u16)(wv&0xffff)), fh = bf2f((u16)(wv>>16));
        sum += fl + fh; ssq += fl*fl + fh*fh;
        wds[q2] = wv;
      }
      int s = hf*8 + sl;
      lsX[px*16 + (s ^ (px&15))] = make_uint4(wds[0],wds[1],wds[2],wds[3]);
    }
    sPart[tid] = make_float2(sum, ssq);
  }
  __syncthreads();
  if (tid < 128){
    float2 A = sPart[tid], B = sPart[tid+128];
    float s = A.x + B.x, q = A.y + B.y;
    float mu = s*(1.f/128.f);
    float var = q*(1.f/128.f) - mu*mu;
    sStat[tid] = make_float2(mu, rsqrtf(fmaxf(var,0.f)+1e-5f));
  }
  __syncthreads();
  {
    float2 st = sStat[px];
    const u32* vp = vbp + ((size_t)b*64 + hf*32)*HW + hwb + px;
    u32 v32[32];
    #pragma unroll
    for (int i=0;i<32;i++) v32[i] = vp[(size_t)i*HW];
    #pragma unroll
    for (int sl=0; sl<8; sl++){
      int s = hf*8 + sl;
      int li = px*16 + (s ^ (px&15));
      uint4 raw = lsX[li];
      u32 wds[4] = {raw.x, raw.y, raw.z, raw.w};
      u32 ow[4];
      #pragma unroll
      for (int q2=0;q2<4;q2++){
        int ch = hf*64 + sl*8 + q2*2;
        float e0 = bf2f((u16)(wds[q2]&0xffff)), e1 = bf2f((u16)(wds[q2]>>16));
        u32 vv = v32[sl*4+q2];
        float v0 = bf2f((u16)(vv&0xffff)), v1 = bf2f((u16)(vv>>16));
        float r0 = ((e0-st.x)*st.y*lnw[ch  ] + lnb[ch  ])*v0;
        float r1 = ((e1-st.x)*st.y*lnw[ch+1] + lnb[ch+1])*v1;
        ow[q2] = pk2(r0, r1);
      }
      lsX[li] = make_uint4(ow[0],ow[1],ow[2],ow[3]);
    }
  }
  __syncthreads();
  int w4 = tid>>6, l = tid&63, g = l>>4, c15 = l&15;
  f32x4 acc[2][4];
  #pragma unroll
  for (int pp=0;pp<2;pp++)
    #pragma unroll
    for (int po=0;po<4;po++) acc[pp][po] = (f32x4){0.f,0.f,0.f,0.f};
  #pragma unroll
  for (int kk=0; kk<4; kk++){
    v8s wf[4], xf[2];
    #pragma unroll
    for (int po=0;po<4;po++){ int row = po*16 + c15; wf[po] = as8(lsW[row*16 + ((kk*4+g) ^ (row&15))]); }
    #pragma unroll
    for (int pp=0;pp<2;pp++){ int row = w4*32 + pp*16 + c15; xf[pp] = as8(lsX[row*16 + ((kk*4+g) ^ (row&15))]); }
    #pragma unroll
    for (int pp=0;pp<2;pp++)
      #pragma unroll
      for (int po=0;po<4;po++)
        acc[pp][po] = __builtin_amdgcn_mfma_f32_16x16x32_bf16(wf[po], xf[pp], acc[pp][po], 0,0,0);
  }
  size_t obase = (size_t)b*64*HW + hwb + w4*32;
  #pragma unroll
  for (int po=0;po<4;po++)
    #pragma unroll
    for (int j=0;j<4;j++){
      int oc = po*16 + g*4 + j;
      const float* xs = x + obase + (size_t)oc*HW + c15;
      float* dp = out + obase + (size_t)oc*HW + c15;
      #pragma unroll
      for (int pp=0;pp<2;pp++) dp[pp*16] = xs[pp*16] + acc[pp][po][j];
    }
}

// ================= ffn epilogue GEMM (K=128): out += Wpo * y3g (pre-gated, pair-u32) =================
__global__ __launch_bounds__(256) void k_gemm_ffn(
    const u32* __restrict__ y3gp, const u16* __restrict__ Wf, float* __restrict__ out,
    int pxbase, int b0)
{
  __shared__ uint4 lsX[128*16];
  __shared__ uint4 lsW[64*16];
  int tid = threadIdx.x;
  int p0 = pxbase + blockIdx.x*128;
  int b = p0 >> 16, hwb = p0 & 65535;
  int px = tid & 127, hf = tid >> 7;
  {
    const uint4* wsrc = (const uint4*)Wf;
    #pragma unroll
    for (int i=0;i<4;i++){
      int idx = i*256 + tid, row = idx>>4, s = idx&15;
      lsW[row*16 + (s ^ (row&15))] = wsrc[idx];
    }
  }
  const u32* yp = y3gp + ((size_t)(b-b0)*64 + hf*32)*HW + hwb + px;
  {
    u32 r32[32];
    #pragma unroll
    for (int i=0;i<32;i++) r32[i] = yp[(size_t)i*HW];
    #pragma unroll
    for (int sl=0; sl<8; sl++){
      int s = hf*8 + sl;
      lsX[px*16 + (s ^ (px&15))] = make_uint4(r32[sl*4+0],r32[sl*4+1],r32[sl*4+2],r32[sl*4+3]);
    }
  }
  __syncthreads();
  int w4 = tid>>6, l = tid&63, g = l>>4, c15 = l&15;
  f32x4 acc[2][4];
  #pragma unroll
  for (int pp=0;pp<2;pp++)
    #pragma unroll
    for (int po=0;po<4;po++) acc[pp][po] = (f32x4){0.f,0.f,0.f,0.f};
  #pragma unroll
  for (int kk=0; kk<4; kk++){
    v8s wf[4], xf[2];
    #pragma unroll
    for (int po=0;po<4;po++){ int row = po*16 + c15; wf[po] = as8(lsW[row*16 + ((kk*4+g) ^ (row&15))]); }
    #pragma unroll
    for (int pp=0;pp<2;pp++){ int row = w4*32 + pp*16 + c15; xf[pp] = as8(lsX[row*16 + ((kk*4+g) ^ (row&15))]); }
    #pragma unroll
    for (int pp=0;pp<2;pp++)
      #pragma unroll
      for (int po=0;po<4;po++)
        acc[pp][po] = __builtin_amdgcn_mfma_f32_16x16x32_bf16(wf[po], xf[pp], acc[pp][po], 0,0,0);
  }
  size_t obase = (size_t)b*64*HW + hwb + w4*32;
  #pragma unroll
  for (int po=0;po<4;po++)
    #pragma unroll
    for (int j=0;j<4;j++){
      int oc = po*16 + g*4 + j;
      float* dp = out + obase + (size_t)oc*HW + c15;
      #pragma unroll
      for (int pp=0;pp<2;pp++) dp[pp*16] = dp[pp*16] + acc[pp][po][j];
    }
}

// ================= pair dw3x3 row-of-8 accumulate, packed f32x2 =================
__device__ __forceinline__ void dw8p_acc2(const u32* __restrict__ sp,
    const float* __restrict__ w9lo, const float* __restrict__ w9hi,
    int h, int w8, f32x2 a2[8])
{
  #pragma unroll
  for (int r=0;r<3;r++){
    int hh = h + r - 1;
    if (hh < 0 || hh > 255) continue;
    const u32* rp = sp + hh*256 + w8;
    uint4 ua = *(const uint4*)rp;
    uint4 ub = *(const uint4*)(rp+4);
    u32 e[8] = {ua.x,ua.y,ua.z,ua.w,ub.x,ub.y,ub.z,ub.w};
    u32 lef = (w8 > 0)   ? rp[-1] : 0u;
    u32 rig = (w8 < 248) ? rp[8]  : 0u;
    f32x2 vm[10];
    vm[0] = up2(lef);
    #pragma unroll
    for (int j=0;j<8;j++) vm[j+1] = up2(e[j]);
    vm[9] = up2(rig);
    f32x2 wa = {w9lo[r*3  ], w9hi[r*3  ]};
    f32x2 wb = {w9lo[r*3+1], w9hi[r*3+1]};
    f32x2 wc = {w9lo[r*3+2], w9hi[r*3+2]};
    #pragma unroll
    for (int j=0;j<8;j++)
      a2[j] += vm[j]*wa + vm[j+1]*wb + vm[j+2]*wc;
  }
}

// ================= 8-point real FFT: x[0..7] -> packed [F0,F1r,F1i,F2r,F2i,F3r,F3i,F4] =================
__device__ __forceinline__ void rfft8(const f32x2 x[8], f32x2 F[8]){
  f32x2 E0 = x[0]+x[2]+x[4]+x[6];
  f32x2 E2 = x[0]-x[2]+x[4]-x[6];
  f32x2 E1r = x[0]-x[4], E1i = x[6]-x[2];
  f32x2 O0 = x[1]+x[3]+x[5]+x[7];
  f32x2 O2 = x[1]-x[3]+x[5]-x[7];
  f32x2 O1r = x[1]-x[5], O1i = x[7]-x[3];
  const float C = 0.70710678118654752f;
  f32x2 s = (O1r+O1i)*C, d = (O1i-O1r)*C;
  F[0] = E0+O0;
  F[1] = E1r+s;  F[2] = E1i+d;
  F[3] = E2;     F[4] = -O2;
  F[5] = E1r-s;  F[6] = d-E1i;
  F[7] = E0-O0;
}

// ================= depthwise 3x3 pair (v path), parameterized source layout =================
__global__ __launch_bounds__(256) void k_dw8p(
    const u32* __restrict__ src, const float* __restrict__ wgt, int c0,
    u32* __restrict__ dstp, int dstOffP, int prMask, int prShift, int srcStride, int srcBase)
{
  int t = blockIdx.x*256 + threadIdx.x;
  int w8 = (t & 31)*8, h = (t>>5) & 255;
  int plane = t >> 13;
  int pr = plane & prMask, b = plane >> prShift;
  const u32* sp = src + ((size_t)(b*srcStride + srcBase + pr))*HW;
  const float* w9 = wgt + (size_t)(c0 + 2*pr)*9;
  f32x2 a2[8];
  #pragma unroll
  for (int j=0;j<8;j++) a2[j] = (f32x2){0.f,0.f};
  dw8p_acc2(sp, w9, w9+9, h, w8, a2);
  u32* dp = dstp + ((size_t)(b*64 + dstOffP + pr))*HW + h*256 + w8;
  uint4 s0, s1;
  s0.x=pk2(a2[0].x,a2[0].y); s0.y=pk2(a2[1].x,a2[1].y); s0.z=pk2(a2[2].x,a2[2].y); s0.w=pk2(a2[3].x,a2[3].y);
  s1.x=pk2(a2[4].x,a2[4].y); s1.y=pk2(a2[5].x,a2[5].y); s1.z=pk2(a2[6].x,a2[6].y); s1.w=pk2(a2[7].x,a2[7].y);
  *(uint4*)dp = s0; *(uint4*)(dp+4) = s1;
}

// ================= DFFN: pair dw3x3 on a & gate halves + GELU gate -> Y3Gp =================
__global__ __launch_bounds__(256) void k_dw8gp(
    const u32* __restrict__ Y0p, const float* __restrict__ wgt, u32* __restrict__ Y3gp)
{
  int t = blockIdx.x*256 + threadIdx.x;
  int w8 = (t & 31)*8, h = (t>>5) & 255;
  int pc = t >> 13;
  int pr = pc & 63, bl = pc >> 6;
  const u32* spA = Y0p + ((size_t)(bl*128 + pr))*HW;
  const u32* spG = Y0p + ((size_t)(bl*128 + 64 + pr))*HW;
  const float* w9a = wgt + (size_t)(2*pr)*9;
  const float* w9g = wgt + (size_t)(128 + 2*pr)*9;
  f32x2 aA[8], aG[8];
  #pragma unroll
  for (int j=0;j<8;j++){ aA[j] = (f32x2){0.f,0.f}; aG[j] = (f32x2){0.f,0.f}; }
  dw8p_acc2(spA, w9a, w9a+9, h, w8, aA);
  dw8p_acc2(spG, w9g, w9g+9, h, w8, aG);
  u32* dp = Y3gp + ((size_t)(bl*64 + pr))*HW + h*256 + w8;
  uint4 s0, s1;
  s0.x=pk2(gelu_exact(aA[0].x)*aG[0].x, gelu_exact(aA[0].y)*aG[0].y);
  s0.y=pk2(gelu_exact(aA[1].x)*aG[1].x, gelu_exact(aA[1].y)*aG[1].y);
  s0.z=pk2(gelu_exact(aA[2].x)*aG[2].x, gelu_exact(aA[2].y)*aG[2].y);
  s0.w=pk2(gelu_exact(aA[3].x)*aG[3].x, gelu_exact(aA[3].y)*aG[3].y);
  s1.x=pk2(gelu_exact(aA[4].x)*aG[4].x, gelu_exact(aA[4].y)*aG[4].y);
  s1.y=pk2(gelu_exact(aA[5].x)*aG[5].x, gelu_exact(aA[5].y)*aG[5].y);
  s1.z=pk2(gelu_exact(aA[6].x)*aG[6].x, gelu_exact(aA[6].y)*aG[6].y);
  s1.w=pk2(gelu_exact(aA[7].x)*aG[7].x, gelu_exact(aA[7].y)*aG[7].y);
  *(uint4*)dp = s0; *(uint4*)(dp+4) = s1;
}

// ===== fused dw(q), dw(k) + per-patch circular conv via row-FFT (freq-domain accumulate) =====
// LDS holds per-row packed rFFT coefficients [F0,F1r,F1i,F2r,F2i,F3r,F3i,F4] as f32x2 (2 channels)
__global__ __launch_bounds__(256) void k_circqk4(
    const u32* __restrict__ bq, const u32* __restrict__ bk,
    const float* __restrict__ dwq, const float* __restrict__ dwk, int c0,
    u32* __restrict__ orawp, int oprBase, int cpb)
{
  __shared__ f32x2 qd[8][288];
  __shared__ f32x2 kd[8][288];
  int tid = threadIdx.x;
  int p = tid & 31, i = tid >> 5;
  int pr = blockIdx.y, b = blockIdx.z;
  int h0 = blockIdx.x*8;
  const u32* qp = bq + ((size_t)(b*cpb+pr))*HW;
  const u32* kp = bk + ((size_t)(b*cpb+pr))*HW;
  const float* wq9 = dwq + (size_t)(c0 + 2*pr)*9;
  const float* wk9 = dwk + (size_t)(c0 + 2*pr)*9;
  {
    f32x2 a2[8], F[8];
    #pragma unroll
    for (int j=0;j<8;j++) a2[j] = (f32x2){0.f,0.f};
    dw8p_acc2(qp, wq9, wq9+9, h0+i, p*8, a2);
    rfft8(a2, F);
    #pragma unroll
    for (int j=0;j<8;j++) qd[i][p*9+j] = F[j];
  }
  {
    f32x2 a2[8], F[8];
    #pragma unroll
    for (int j=0;j<8;j++) a2[j] = (f32x2){0.f,0.f};
    dw8p_acc2(kp, wk9, wk9+9, h0+i, p*8, a2);
    rfft8(a2, F);
    #pragma unroll
    for (int j=0;j<8;j++) kd[i][p*9+j] = F[j];
  }
  __syncthreads();
  // freq-domain accumulate: A = sum_u Fq[u] * Fk[(i-u)&7]  (Hermitian-packed bins)
  f32x2 A[8];
  #pragma unroll
  for (int j=0;j<8;j++) A[j] = (f32x2){0.f,0.f};
  #pragma unroll
  for (int u=0;u<8;u++){
    int ku = (i-u)&7;
    const f32x2* Q = &qd[u][p*9];
    const f32x2* K = &kd[ku][p*9];
    f32x2 q0=Q[0],q1=Q[1],q2=Q[2],q3=Q[3],q4=Q[4],q5=Q[5],q6=Q[6],q7=Q[7];
    f32x2 k0=K[0],k1=K[1],k2=K[2],k3=K[3],k4=K[4],k5=K[5],k6=K[6],k7=K[7];
    A[0] += q0*k0;
    A[1] += q1*k1 - q2*k2;  A[2] += q1*k2 + q2*k1;
    A[3] += q3*k3 - q4*k4;  A[4] += q3*k4 + q4*k3;
    A[5] += q5*k5 - q6*k6;  A[6] += q5*k6 + q6*k5;
    A[7] += q7*k7;
  }
  // inverse real DFT (length 8, scale 1/8)
  const float C = 0.70710678118654752f;
  const float IV = 0.125f;
  f32x2 a0=A[0], b4=A[7], r1=A[1], i1=A[2], r2=A[3], i2=A[4], r3=A[5], i3=A[6];
  f32x2 t0 = a0+b4, t1 = a0-b4;
  f32x2 o[8];
  o[0] = (t0 + (r1+r2+r3)*2.f)*IV;
  o[1] = (t1 + ((r1-i1)*C - i2 - (r3+i3)*C)*2.f)*IV;
  o[2] = (t0 + (i3-i1-r2)*2.f)*IV;
  o[3] = (t1 + (i2 - (r1+i1)*C + (r3-i3)*C)*2.f)*IV;
  o[4] = (t0 + (r2-r1-r3)*2.f)*IV;
  o[5] = (t1 + ((i1-r1)*C - i2 + (r3+i3)*C)*2.f)*IV;
  o[6] = (t0 + (i1-r2-i3)*2.f)*IV;
  o[7] = (t1 + ((r1+i1)*C + i2 + (i3-r3)*C)*2.f)*IV;
  u32* op = orawp + ((size_t)(b*64 + oprBase + pr))*HW + (size_t)(h0+i)*256 + p*8;
  uint4 s0, s1;
  s0.x=pk2(o[0].x,o[0].y); s0.y=pk2(o[1].x,o[1].y); s0.z=pk2(o[2].x,o[2].y); s0.w=pk2(o[3].x,o[3].y);
  s1.x=pk2(o[4].x,o[4].y); s1.y=pk2(o[5].x,o[5].y); s1.z=pk2(o[6].x,o[6].y); s1.w=pk2(o[7].x,o[7].y);
  *(uint4*)op = s0; *(uint4*)(op+4) = s1;
}

// ================= DFFN spectral circ conv as per-channel 64x64 GEMM (MFMA), in-place =================
__global__ __launch_bounds__(256) void k_circg_mfma(
    u32* __restrict__ y, const u16* __restrict__ CM)
{
  __shared__ uint4 lsA[2][64*8];
  __shared__ uint4 lsB[2][64*8];
  int tid = threadIdx.x;
  int pr = blockIdx.y, b = blockIdx.z;
  int h0 = blockIdx.x*16;
  u32* plane = y + ((size_t)(b*128+pr))*HW;
  {
    const uint4* cmsrc = (const uint4*)(CM + (size_t)(2*pr)*4096);
    #pragma unroll
    for (int t=0; t<4; t++){
      int idx = t*256 + tid;
      int ch = idx >> 9, e = idx & 511;
      int row = e >> 3, s = e & 7;
      lsA[ch][row*8 + (s ^ (row&7))] = cmsrc[ch*512 + e];
    }
  }
  {
    #pragma unroll
    for (int t=0; t<2; t++){
      int rr = t*256 + tid;
      int n = rr >> 3, i = rr & 7;
      const u32* rp = plane + (size_t)(h0 + (n>>5)*8 + i)*256 + (n&31)*8;
      uint4 ua = *(const uint4*)rp;
      uint4 ub = *(const uint4*)(rp+4);
      u32 e[8] = {ua.x,ua.y,ua.z,ua.w,ub.x,ub.y,ub.z,ub.w};
      uint4 L, H;
      L.x = (e[0]&0xffffu) | (e[1]<<16);
      L.y = (e[2]&0xffffu) | (e[3]<<16);
      L.z = (e[4]&0xffffu) | (e[5]<<16);
      L.w = (e[6]&0xffffu) | (e[7]<<16);
      H.x = (e[0]>>16) | (e[1]&0xffff0000u);
      H.y = (e[2]>>16) | (e[3]&0xffff0000u);
      H.z = (e[4]>>16) | (e[5]&0xffff0000u);
      H.w = (e[6]>>16) | (e[7]&0xffff0000u);
      lsB[0][n*8 + (i ^ (n&7))] = L;
      lsB[1][n*8 + (i ^ (n&7))] = H;
    }
  }
  __syncthreads();
  int w = tid>>6, l = tid&63, g = l>>4, c15 = l&15;
  f32x4 acc[2][4];
  #pragma unroll
  for (int ch=0;ch<2;ch++)
    #pragma unroll
    for (int po=0;po<4;po++) acc[ch][po] = (f32x4){0.f,0.f,0.f,0.f};
  #pragma unroll
  for (int kk=0; kk<2; kk++){
    v8s bfr[2];
    { int row = w*16 + c15;
      bfr[0] = as8(lsB[0][row*8 + ((kk*4+g) ^ (row&7))]);
      bfr[1] = as8(lsB[1][row*8 + ((kk*4+g) ^ (row&7))]); }
    #pragma unroll
    for (int po=0;po<4;po++){
      int row = po*16 + c15;
      v8s aL = as8(lsA[0][row*8 + ((kk*4+g) ^ (row&7))]);
      v8s aH = as8(lsA[1][row*8 + ((kk*4+g) ^ (row&7))]);
      acc[0][po] = __builtin_amdgcn_mfma_f32_16x16x32_bf16(aL, bfr[0], acc[0][po], 0,0,0);
      acc[1][po] = __builtin_amdgcn_mfma_f32_16x16x32_bf16(aH, bfr[1], acc[1][po], 0,0,0);
    }
  }
  int patch = w*16 + c15;
  u32* pbase = plane + (size_t)(h0 + (patch>>5)*8)*256 + (patch&31)*8;
  #pragma unroll
  for (int po=0;po<4;po++){
    int oh = po*2 + (g>>1), ow4 = 4*(g&1);
    uint4 sv;
    sv.x = pk2(acc[0][po][0], acc[1][po][0]);
    sv.y = pk2(acc[0][po][1], acc[1][po][1]);
    sv.z = pk2(acc[0][po][2], acc[1][po][2]);
    sv.w = pk2(acc[0][po][3], acc[1][po][3]);
    *(uint4*)(pbase + (size_t)oh*256 + ow4) = sv;
  }
}

extern "C" void kernel_launch(void* const* d_in, const int* in_sizes, int n_in,
                              void* d_out, int out_size, void* d_ws, size_t ws_size,
                              hipStream_t stream)
{
  const float* x       = (const float*)d_in[0];
  const float* evt     = (const float*)d_in[1];
  const float* ln1i_w  = (const float*)d_in[2];
  const float* ln1i_b  = (const float*)d_in[3];
  const float* ln1e_w  = (const float*)d_in[4];
  const float* ln1e_b  = (const float*)d_in[5];
  const float* w_q     = (const float*)d_in[6];
  const float* dw_q    = (const float*)d_in[7];
  const float* w_kv    = (const float*)d_in[8];
  const float* dw_kv   = (const float*)d_in[9];
  const float* lnA_w   = (const float*)d_in[10];
  const float* lnA_b   = (const float*)d_in[11];
  const float* w_po_at = (const float*)d_in[12];
  const float* ln2_w   = (const float*)d_in[13];
  const float* ln2_b   = (const float*)d_in[14];
  const float* w_pi    = (const float*)d_in[15];
  const float* fft_par = (const float*)d_in[16];
  const float* dw_ffn  = (const float*)d_in[17];
  const float* w_poffn = (const float*)d_in[18];
  float* out = (float*)d_out;

  char* ws = (char*)d_ws;
  const size_t MiB = 1048576ull;
  bool big = (ws_size >= 200*MiB);
  size_t smOff = big ? 192*MiB : 160*MiB;
  char* sm = ws + smOff;
  float* G    = (float*)(sm);                   // 64 KiB
  u16* WQF    = (u16*)(sm + 65536);
  u16* WKVF   = (u16*)(sm + 81920);
  u16* WPIF   = (u16*)(sm + 114688);
  u16* WPAF   = (u16*)(sm + 147456);
  u16* WPFF   = (u16*)(sm + 163840);
  float* AQ   = (float*)(sm + 180224);
  float* BQ   = (float*)(sm + 180736);
  float* AKV  = (float*)(sm + 181248);
  float* BKV  = (float*)(sm + 182272);
  float* API  = (float*)(sm + 183296);
  float* BPI  = (float*)(sm + 184320);
  u16* CMAT   = (u16*)(sm + 1*MiB);             // 2 MiB

  dim3 blk256(256);

  k_prep<<<69, blk256, 0, stream>>>(fft_par, G,
      w_q, ln1i_w, ln1i_b, WQF, AQ, BQ,
      w_kv, ln1e_w, ln1e_b, WKVF, AKV, BKV,
      w_pi, ln2_w, ln2_b, WPIF, API, BPI,
      w_po_at, WPAF, w_poffn, WPFF);
  k_prep2<<<256, blk256, 0, stream>>>(G, CMAT);

  if (big){
    // merged layout: QBUF 0..64, KBUF 64..128, ORAW 128..192 (MiB)
    u32* QBUF  = (u32*)(ws);
    u32* KBUF  = (u32*)(ws + 64*MiB);
    u32* ORAWp = (u32*)(ws + 128*MiB);
    u32* PV    = (u32*)(ws + 64*MiB);    // over KBUF (dead after circqk)
    u32* VBUFp = (u32*)(ws);             // over QBUF (dead after circqk)
    u32* Y0p   = (u32*)(ws);             // (4,128,HW) u32 = 128 MiB, over QBUF+KBUF (dead after attn)
    u32* Y3Gp  = (u32*)(ws + 128*MiB);   // (4,64,HW) u32 = 64 MiB, over ORAW (dead after attn)

    GA qa = {x,   WQF,  AQ,  BQ,  QBUF, 0, 0, 64, 0, 0};
    GA ka = {evt, WKVF, AKV, BKV, KBUF, 0, 0, 64, 0, 0};
    k_gemm64<2><<<dim3(2048,2,1), blk256, 0, stream>>>(qa, ka);
    k_circqk4<<<dim3(32,64,4), blk256, 0, stream>>>(QBUF, KBUF, dw_q, dw_kv, 0, ORAWp, 0, 64);
    GA va = {evt, WKVF, AKV, BKV, PV, 128, 0, 64, 0, 0};
    k_gemm64<2><<<dim3(2048,1,1), blk256, 0, stream>>>(va, va);
    k_dw8p<<<8192, blk256, 0, stream>>>(PV, dw_kv, 128, VBUFp, 0, 63, 6, 64, 0);
    k_gemm_attn<<<2048, blk256, 0, stream>>>(x, ORAWp, VBUFp, lnA_w, lnA_b, WPAF, out);
    // ---- DFFN merged over all 4 batches ----
    GA pa = {out, WPIF, API, BPI, Y0p, 0, 0, 128, 0, 0};
    k_gemm64<4><<<dim3(2048,1,1), blk256, 0, stream>>>(pa, pa);
    k_circg_mfma<<<dim3(16,128,4), blk256, 0, stream>>>(Y0p, CMAT);
    k_dw8gp<<<8192, blk256, 0, stream>>>(Y0p, dw_ffn, Y3Gp);
    k_gemm_ffn<<<2048, blk256, 0, stream>>>(Y3Gp, WPFF, out, 0, 0);
  } else {
    // fallback: chunked layout (peak 163 MiB, proven)
    u32* P1p   = (u32*)(ws);
    u32* ORAWp = (u32*)(ws + 32*MiB);
    u32* P2p   = (u32*)(ws + 96*MiB);
    u32* VBUFp = (u32*)(ws + 96*MiB);
    u32* Y0p   = (u32*)(ws);
    u32* Y3Gp  = (u32*)(ws + 64*MiB);

    for (int i=0;i<2;i++){
      GA qa = {x,   WQF,  AQ,  BQ,  P1p, 64*i, 0, 32, 0, 0};
      GA ka = {evt, WKVF, AKV, BKV, P2p, 64*i, 0, 32, 0, 0};
      k_gemm64<1><<<dim3(2048,2,1), blk256, 0, stream>>>(qa, ka);
      k_circqk4<<<dim3(32,32,4), blk256, 0, stream>>>(P1p, P2p, dw_q, dw_kv, 64*i, ORAWp, 32*i, 32);
    }
    for (int i=0;i<2;i++){
      GA va = {evt, WKVF, AKV, BKV, P1p, 128+64*i, 0, 32, 0, 0};
      k_gemm64<1><<<dim3(2048,1,1), blk256, 0, stream>>>(va, va);
      k_dw8p<<<4096, blk256, 0, stream>>>(P1p, dw_kv, 128+64*i, VBUFp, 32*i, 31, 5, 32, 0);
    }
    k_gemm_attn<<<2048, blk256, 0, stream>>>(x, ORAWp, VBUFp, lnA_w, lnA_b, WPAF, out);
    for (int h=0;h<2;h++){
      GA pa = {out, WPIF, API, BPI, Y0p, 0, 0, 128, 2*h, h*131072};
      k_gemm64<4><<<dim3(1024,1,1), blk256, 0, stream>>>(pa, pa);
      k_circg_mfma<<<dim3(16,128,2), blk256, 0, stream>>>(Y0p, CMAT);
      k_dw8gp<<<4096, blk256, 0, stream>>>(Y0p, dw_ffn, Y3Gp);
      k_gemm_ffn<<<1024, blk256, 0, stream>>>(Y3Gp, WPFF, out, h*131072, 2*h);
    }
  }
}